// Round 11
// baseline (371.853 us; speedup 1.0000x reference)
//
#include <hip/hip_runtime.h>
#include <math.h>

#define Bb 16
#define Cc 256
#define Nn 1024
#define Mm 256
#define NHh 8
#define HDd 32
#define HIDh 24
#define NMs (Nn*Mm)
#define TTB 16
#define EPSf 1e-5f
#define SCALEf 0.17677669529663687f   // 1/sqrt(32)
#define STP 32   // stats padding stride (floats) = 128B cacheline

typedef float v2f __attribute__((ext_vector_type(2)));
typedef __attribute__((ext_vector_type(8))) short bf8v;   // 8 bf16 (4 VGPRs)
typedef __attribute__((ext_vector_type(4))) float f4v;

__device__ __forceinline__ float wave_sum(float v){
#pragma unroll
  for (int off=32; off; off>>=1) v += __shfl_xor(v, off, 64);
  return v;
}
// fast sigmoid: v_exp + v_rcp (rel err ~2^-22, far below bf16 storage error)
__device__ __forceinline__ float sigm_(float x){ return __builtin_amdgcn_rcpf(1.f + __expf(-x)); }
__device__ __forceinline__ float swish_(float x){ return x * sigm_(x); }
__device__ __forceinline__ v2f swish2(v2f x){
  v2f r;
  r.x = x.x * sigm_(x.x);
  r.y = x.y * sigm_(x.y);
  return r;
}
__device__ __forceinline__ unsigned short f2bf(float f){
  unsigned u = __float_as_uint(f);
  u += 0x7fffu + ((u >> 16) & 1u);          // round-to-nearest-even
  return (unsigned short)(u >> 16);
}
// packed f32x2 -> bf16x2 convert (RNE, single instruction) — lo in [15:0], hi in [31:16]
__device__ __forceinline__ unsigned cvtpk(float lo, float hi){
  unsigned r;
  asm("v_cvt_pk_bf16_f32 %0, %1, %2" : "=v"(r) : "v"(lo), "v"(hi));
  return r;
}
__device__ __forceinline__ float bfup(unsigned short s){ return __uint_as_float(((unsigned)s) << 16); }
__device__ __forceinline__ float bflo(unsigned u){ return __uint_as_float(u << 16); }
__device__ __forceinline__ float bfhi(unsigned u){ return __uint_as_float(u & 0xffff0000u); }
// async global->LDS DMA, 16 B per lane; LDS dest is wave-uniform base + lane*16
__device__ __forceinline__ void gload_lds16(const void* g, void* l){
  __builtin_amdgcn_global_load_lds(
      (const __attribute__((address_space(1))) unsigned int*)g,
      (__attribute__((address_space(3))) unsigned int*)l, 16, 0, 0);
}

// ------------- MFMA GEMM: O[b,j,i] = sum_k W[j,k]*A[b,k,i] --------------
// MODE 0: linear f32 store O1[(b*Cc+j)*Nn+i]          (q-projection, Isize=Nn)
// MODE 1: scatter j->(two,h,d), store BF16 to O1/O2    (kv-projection, Isize=Mm)
// MODE 2: MODE0 + bias                                 (out-projection, Isize=Nn)
// 64x64 tile, 4 waves of 32x32. Fragment layouts (m89/m91, proven R6-R10):
//   A/B frag: idx=l&15, k=(l>>4)*8+e | D: col=l&15, row=(l>>4)*4+r
template<int MODE>
__launch_bounds__(256)
__global__ void gemm_mfma(const float* __restrict__ A,   // [b][k][i], i-stride 1, k-stride Isize
                          const float* __restrict__ W,   // [j][k], k-stride Cc
                          const float* __restrict__ bias,
                          float* __restrict__ O1, float* __restrict__ O2, int Isize)
{
  __shared__ __align__(16) unsigned short Wt[64 * 40];   // [j][k0..31] +8 pad
  __shared__ __align__(16) unsigned short At[64 * 40];   // [i][k0..31] +8 pad (transposed A)
  const int b = blockIdx.z;
  const int i0 = blockIdx.x * 64;
  const int j0 = blockIdx.y * 64;
  const int tid = threadIdx.x;
  const int lane = tid & 63, wv = tid >> 6;
  const int wj = (wv >> 1) * 32, wi = (wv & 1) * 32;
  const int l15 = lane & 15, l4 = lane >> 4;

  const float* Ab = A + (long)b * Cc * Isize;
  const int sj = tid >> 2, skh = (tid & 3) * 8;    // W staging: row j, 8-k block
  const int si = tid & 63, skb = (tid >> 6) * 8;   // A staging: col i, 8-k block

  f4v acc[2][2] = {};
  for (int k0 = 0; k0 < Cc; k0 += 32) {
    float wreg[8];
    {
      const float* wp = W + (long)(j0 + sj) * Cc + k0 + skh;
      *(f4v*)&wreg[0] = *(const f4v*)&wp[0];
      *(f4v*)&wreg[4] = *(const f4v*)&wp[4];
    }
    float areg[8];
    {
      const float* ap = Ab + (long)(k0 + skb) * Isize + i0 + si;
#pragma unroll
      for (int e = 0; e < 8; e++) areg[e] = ap[(long)e * Isize];   // coalesced across lanes
    }
    __syncthreads();   // previous compute done reading LDS
    {
      unsigned pk[4];
#pragma unroll
      for (int t = 0; t < 4; t++) pk[t] = cvtpk(wreg[2*t], wreg[2*t+1]);
      *(uint4*)&Wt[sj*40 + skh] = make_uint4(pk[0], pk[1], pk[2], pk[3]);
#pragma unroll
      for (int t = 0; t < 4; t++) pk[t] = cvtpk(areg[2*t], areg[2*t+1]);
      *(uint4*)&At[si*40 + skb] = make_uint4(pk[0], pk[1], pk[2], pk[3]);
    }
    __syncthreads();   // tile staged
    bf8v af[2], bf[2];
#pragma unroll
    for (int fm = 0; fm < 2; fm++)
      af[fm] = *(const bf8v*)&Wt[(wj + fm*16 + l15)*40 + l4*8];
#pragma unroll
    for (int fn = 0; fn < 2; fn++)
      bf[fn] = *(const bf8v*)&At[(wi + fn*16 + l15)*40 + l4*8];
#pragma unroll
    for (int fm = 0; fm < 2; fm++)
#pragma unroll
      for (int fn = 0; fn < 2; fn++)
        acc[fm][fn] = __builtin_amdgcn_mfma_f32_16x16x32_bf16(af[fm], bf[fn], acc[fm][fn], 0, 0, 0);
  }
  // ---- epilogue: D col=l&15 (i), row=(l>>4)*4+r (j) ----
#pragma unroll
  for (int fm = 0; fm < 2; fm++) {
    const int jb = j0 + wj + fm*16 + l4*4;   // j for r=0
    f4v bv = {0.f, 0.f, 0.f, 0.f};
    if (MODE == 2) bv = *(const f4v*)&bias[jb];
#pragma unroll
    for (int fn = 0; fn < 2; fn++) {
      const int ii = i0 + wi + fn*16 + l15;
      if (MODE == 1) {
        // bf16 store: d0..d0+3 consecutive over r, within one head (d0 mult of 4)
        const int two = jb >> 8, jj = jb & 255;
        const int h = jj >> 5, d0 = jj & 31;
        unsigned short* p = (unsigned short*)(two ? O2 : O1)
                          + (((long)b * NHh + h) * Mm + ii) * HDd + d0;
        *(uint2*)p = make_uint2(cvtpk(acc[fm][fn][0], acc[fm][fn][1]),
                                cvtpk(acc[fm][fn][2], acc[fm][fn][3]));
      } else {
        float* op = O1 + ((long)b * Cc + jb) * (long)Isize + ii;
#pragma unroll
        for (int r = 0; r < 4; r++)
          op[(long)r * Isize] = acc[fm][fn][r] + bv[r];
      }
    }
  }
}

// ------------- scores + softmax -> attn (bf16), QK^T via MFMA (proven R8-R10) -------------
__launch_bounds__(256)
__global__ void attn_softmax(const float* __restrict__ qhT, const unsigned short* __restrict__ kb,
                             const float* __restrict__ rpb, unsigned short* __restrict__ attn)
{
  __shared__ __align__(16) unsigned short Kt[Mm * 40];   // [m][d] bf16 +8 pad (20.5 KB)
  __shared__ __align__(16) unsigned short Qt[64 * 40];   // [n][d] bf16 +8 pad (5.1 KB)
  const int b = blockIdx.z, h = blockIdx.y, n0 = blockIdx.x * 64;
  const int tid = threadIdx.x;
  const int lane = tid & 63, wv = tid >> 6;
  const int l15 = lane & 15, l4 = lane >> 4;
  // stage K (bf16 copy): 256 rows x 32 d = 1024 uint4
  {
    const unsigned short* kp = kb + ((long)b * NHh + h) * Mm * HDd;
#pragma unroll
    for (int u = 0; u < 4; u++) {
      const int f = tid + u * 256;
      const int m = f >> 2, q8 = (f & 3) * 8;
      *(uint4*)&Kt[m * 40 + q8] = *(const uint4*)&kp[m * HDd + q8];
    }
  }
  // stage Q^T (bf16): qhT is [d][n]; each thread covers 2 d per n
  {
    const float* qp = qhT + ((long)b * NHh + h) * HDd * Nn + n0;
#pragma unroll
    for (int u = 0; u < 4; u++) {
      const int f = tid + u * 256;
      const int n = f & 63, d2 = (f >> 6) * 2;
      const float q0 = qp[(long)d2 * Nn + n];
      const float q1 = qp[(long)(d2 + 1) * Nn + n];
      *(unsigned*)&Qt[n * 40 + d2] = cvtpk(q0, q1);
    }
  }
  __syncthreads();
  const bf8v qf = *(const bf8v*)&Qt[(wv * 16 + l15) * 40 + l4 * 8];
  f4v S[16];
#pragma unroll
  for (int mt = 0; mt < 16; mt++) {
    const bf8v kf = *(const bf8v*)&Kt[(mt * 16 + l15) * 40 + l4 * 8];
    f4v z = {0.f, 0.f, 0.f, 0.f};
    S[mt] = __builtin_amdgcn_mfma_f32_16x16x32_bf16(kf, qf, z, 0, 0, 0);
  }
  // lane holds S[n][m = mt*16 + l4*4 + r] for fixed n = n0 + wv*16 + l15
  const int n = n0 + wv * 16 + l15;
  const float* rp = rpb + (long)n * Mm;
  float mx = -1e30f;
#pragma unroll
  for (int mt = 0; mt < 16; mt++) {
    const f4v r4 = *(const f4v*)&rp[mt * 16 + l4 * 4];
    S[mt][0] = fmaf(S[mt][0], SCALEf, r4.x);
    S[mt][1] = fmaf(S[mt][1], SCALEf, r4.y);
    S[mt][2] = fmaf(S[mt][2], SCALEf, r4.z);
    S[mt][3] = fmaf(S[mt][3], SCALEf, r4.w);
    mx = fmaxf(mx, fmaxf(fmaxf(S[mt][0], S[mt][1]), fmaxf(S[mt][2], S[mt][3])));
  }
  mx = fmaxf(mx, __shfl_xor(mx, 16, 64));
  mx = fmaxf(mx, __shfl_xor(mx, 32, 64));
  float sum = 0.f;
#pragma unroll
  for (int mt = 0; mt < 16; mt++) {
    S[mt][0] = __expf(S[mt][0] - mx);
    S[mt][1] = __expf(S[mt][1] - mx);
    S[mt][2] = __expf(S[mt][2] - mx);
    S[mt][3] = __expf(S[mt][3] - mx);
    sum += (S[mt][0] + S[mt][1]) + (S[mt][2] + S[mt][3]);
  }
  sum += __shfl_xor(sum, 16, 64);
  sum += __shfl_xor(sum, 32, 64);
  const float inv = __builtin_amdgcn_rcpf(sum);
  unsigned short* ap = attn + (((long)b * NHh + h) * Nn + n) * Mm;
#pragma unroll
  for (int mt = 0; mt < 16; mt++) {
    const unsigned p0 = cvtpk(S[mt][0] * inv, S[mt][1] * inv);
    const unsigned p1 = cvtpk(S[mt][2] * inv, S[mt][3] * inv);
    *(uint2*)&ap[mt * 16 + l4 * 4] = make_uint2(p0, p1);
  }
}

// ------------- Gram matrix G[b][36*STP] (line-spread atomics) -------------
// R22: 2 m-chunks per thread accumulated into the same g[36] -> halves the
// per-element wave_sum overhead (36 x 6 shfl+add was ~as costly as the FMAs).
__launch_bounds__(256)
__global__ void gram_stats(const unsigned short* __restrict__ attn, float* __restrict__ G)
{
  __shared__ float red[36][4];
  const int b = blockIdx.y, tid = threadIdx.x;
  const unsigned short* ap = attn + (long)b * NHh * NMs + (long)blockIdx.x * 4096 + tid * 8;
  float g[36] = {};
#pragma unroll
  for (int half = 0; half < 2; half++) {
    const unsigned short* app = ap + half * 2048;
    float a[8][8];
#pragma unroll
    for (int h = 0; h < 8; h++) {
      const uint4 v = *(const uint4*)&app[(long)h * NMs];
      a[h][0] = bflo(v.x); a[h][1] = bfhi(v.x); a[h][2] = bflo(v.y); a[h][3] = bfhi(v.y);
      a[h][4] = bflo(v.z); a[h][5] = bfhi(v.z); a[h][6] = bflo(v.w); a[h][7] = bfhi(v.w);
    }
    int t = 0;
#pragma unroll
    for (int i = 0; i < 8; i++)
#pragma unroll
      for (int j = i; j < 8; j++, t++) {
        float s = 0.f;
#pragma unroll
        for (int m = 0; m < 8; m++) s = fmaf(a[i][m], a[j][m], s);
        g[t] += s;
      }
  }
  const int lane = tid & 63, wid = tid >> 6;
#pragma unroll
  for (int t2 = 0; t2 < 36; t2++) {
    const float s = wave_sum(g[t2]);
    if (lane == 0) red[t2][wid] = s;
  }
  __syncthreads();
  if (tid < 36)
    atomicAdd(&G[((long)b * 36 + tid) * STP],
              red[tid][0] + red[tid][1] + red[tid][2] + red[tid][3]);
}

// ------------- pass B: expand+gn1(from G)+swish -> conv3x3 -> x2(bf16) + gn2 stats ----
// R18/R7 inner loop (proven). R22: grid y = runtime chunk (16 when workspace allows)
// -> 1024 blocks in ONE launch = 4/CU (2 resident + 2 queued) so finishing blocks
// backfill continuously (the 512-block/launch config had zero queue depth).
__launch_bounds__(768, 6)
__global__ void dla_pass_b(const unsigned short* __restrict__ attn,
                           const float* __restrict__ Wexp,
                           const float* __restrict__ g1, const float* __restrict__ b1,
                           const float* __restrict__ G, const float* __restrict__ Wdw,
                           unsigned short* __restrict__ x2, float* __restrict__ stats2c, int b0)
{
  __shared__ __align__(16) unsigned short sl[(TTB + 2) * NHh * Mm];  // 73728 B
  const int tid = threadIdx.x;
  const int wv = tid >> 6, lane = tid & 63;   // wv 0..11
  const int bc = blockIdx.y, b = b0 + bc;
  const int n0 = blockIdx.x * TTB;
  const int c0 = wv * 2;        // channel pair owned by this wave
  const int g = wv >> 2;        // GN group (channels 0-7 / 8-15 / 16-23)

  // ---- issue async staging FIRST so DMA overlaps the Gram/weight preamble ----
  {
    const unsigned short* abase = attn + (long)b * NHh * NMs;
    const int q_lo = lane >> 5;         // which plane of the pair this lane fills
    const int m0 = (lane & 31) * 8;     // ushort offset within the 512 B plane
#pragma unroll
    for (int i = 0; i < 6; i++) {
      const int pp = (wv * 6 + i) * 2;  // even plane index; pp,pp+1 share a row
      const int row = pp >> 3;
      const int nn = n0 - 1 + row;
      if (nn >= 0 && nn < Nn) {
        const int h = (pp + q_lo) & 7;
        gload_lds16(abase + (long)h * NMs + (long)nn * Mm + m0, &sl[pp * Mm]);
      }
    }
  }

  // gn1 stats from Gram matrix (mean exact: softmax rows sum to 1)
  float mu, rs;
  {
    const float* Gb = G + (long)b * 36 * STP;
    float sum = 0.f, sumsq = 0.f;
    for (int c = g * 8; c < g * 8 + 8; c++) {
      float w[8];
#pragma unroll
      for (int h = 0; h < 8; h++) w[h] = Wexp[c * 8 + h];
      float wsu = 0.f;
#pragma unroll
      for (int h = 0; h < 8; h++) wsu += w[h];
      sum += wsu;
      float s2 = 0.f;
      int t = 0;
#pragma unroll
      for (int i = 0; i < 8; i++)
#pragma unroll
        for (int j = i; j < 8; j++, t++) {
          const float f = (i == j) ? 1.f : 2.f;
          s2 = fmaf(f * w[i] * w[j], Gb[t * STP], s2);
        }
      sumsq += s2;
    }
    const float cnt = 8.f * NMs;
    mu = sum * ((float)Nn / cnt);
    const float var = sumsq / cnt - mu * mu;
    rs = rsqrtf(var + EPSf);
  }
  // channel-pair (v2f) weights: lane .x -> c0, lane .y -> c0+1 (wave-uniform)
  v2f we2[8], wd2[9], B12;
  {
    const float A10 = rs * g1[c0], A11 = rs * g1[c0 + 1];
    B12.x = b1[c0] - mu * A10;
    B12.y = b1[c0 + 1] - mu * A11;
#pragma unroll
    for (int h = 0; h < NHh; h++) {
      we2[h].x = Wexp[c0 * NHh + h] * A10;
      we2[h].y = Wexp[(c0 + 1) * NHh + h] * A11;
    }
#pragma unroll
    for (int k = 0; k < 9; k++) {
      wd2[k].x = Wdw[c0 * 9 + k];
      wd2[k].y = Wdw[(c0 + 1) * 9 + k];
    }
  }
  __syncthreads();   // the only barrier: drains the DMA (vmcnt(0)) + all waves staged

  v2f s1p[4] = {}, s2p[4] = {};
  v2f smp = {0.f, 0.f}, sqp = {0.f, 0.f};
  for (int r = -1; r <= TTB; r++) {
    const int nn = n0 + r;
    const bool rowv = (nn >= 0 && nn < Nn);
    v2f xp[4];
    if (rowv) {
#pragma unroll
      for (int mi = 0; mi < 4; mi++) xp[mi] = B12;
      const unsigned short* sp = &sl[(r + 1) * NHh * Mm + lane * 4];
#pragma unroll
      for (int h = 0; h < NHh; h++) {
        const ushort4 v = *(const ushort4*)&sp[h * Mm];   // ds_read_b64, 2-way alias
        xp[0] += we2[h] * bfup(v.x);
        xp[1] += we2[h] * bfup(v.y);
        xp[2] += we2[h] * bfup(v.z);
        xp[3] += we2[h] * bfup(v.w);
      }
#pragma unroll
      for (int mi = 0; mi < 4; mi++) xp[mi] = swish2(xp[mi]);
    } else {
#pragma unroll
      for (int mi = 0; mi < 4; mi++) xp[mi] = (v2f){0.f, 0.f};
    }
    // horizontal halo via shuffles (per component; shfl is 32-bit)
    v2f xl, xr;
    xl.x = __shfl_up(xp[3].x, 1);  xl.y = __shfl_up(xp[3].y, 1);
    xr.x = __shfl_down(xp[0].x, 1); xr.y = __shfl_down(xp[0].y, 1);
    if (lane == 0)  { xl = (v2f){0.f, 0.f}; }
    if (lane == 63) { xr = (v2f){0.f, 0.f}; }
    const v2f L[4] = {xl, xp[0], xp[1], xp[2]};
    const v2f R[4] = {xp[1], xp[2], xp[3], xr};
    v2f y[4];
#pragma unroll
    for (int mi = 0; mi < 4; mi++) {
      const v2f u0 = wd2[0] * L[mi] + wd2[1] * xp[mi] + wd2[2] * R[mi];
      const v2f u1 = wd2[3] * L[mi] + wd2[4] * xp[mi] + wd2[5] * R[mi];
      const v2f u2 = wd2[6] * L[mi] + wd2[7] * xp[mi] + wd2[8] * R[mi];
      y[mi] = s2p[mi] + u2;
      s2p[mi] = s1p[mi] + u1;
      s1p[mi] = u0;
    }
    if (r >= 1) {
#pragma unroll
      for (int mi = 0; mi < 4; mi++) {
        smp += y[mi];
        sqp += y[mi] * y[mi];
      }
      const int nw = n0 + r - 1;
      const unsigned w0 = cvtpk(y[0].x, y[1].x), w1 = cvtpk(y[2].x, y[3].x);
      const unsigned w2 = cvtpk(y[0].y, y[1].y), w3 = cvtpk(y[2].y, y[3].y);
      unsigned short* xq = x2 + ((long)(bc * Nn + nw) * HIDh + c0) * Mm + lane * 4;
      *(uint2*)xq        = make_uint2(w0, w1);   // channel c0
      *(uint2*)(xq + Mm) = make_uint2(w2, w3);   // channel c0+1
    }
  }
  {
    const float vs0 = wave_sum(smp.x), vq0 = wave_sum(sqp.x);
    const float vs1 = wave_sum(smp.y), vq1 = wave_sum(sqp.y);
    if (lane == 0) {
      atomicAdd(&stats2c[((long)b * HIDh + c0) * STP], vs0);
      atomicAdd(&stats2c[((long)b * HIDh + c0) * STP + 1], vq0);
      atomicAdd(&stats2c[((long)b * HIDh + c0 + 1) * STP], vs1);
      atomicAdd(&stats2c[((long)b * HIDh + c0 + 1) * STP + 1], vq1);
    }
  }
}

// ------------- pass C: gn2+swish + 1x1 reduce -> a2(bf16) + partial gn3 stats -------
// R21 m-pair packed accumulate (proven R10).
__launch_bounds__(256)
__global__ void dla_pass_c(const unsigned short* __restrict__ x2, const float* __restrict__ g2,
                           const float* __restrict__ b2, const float* __restrict__ stats2c,
                           const float* __restrict__ Wred, unsigned short* __restrict__ a2,
                           float* __restrict__ partial3, int b0)
{
  __shared__ float wA[HIDh], wB[HIDh], wrs[HIDh][NHh];
  __shared__ float red2s[2][4];
  const int tid = threadIdx.x;
  const int wv = tid >> 6, lane = tid & 63;
  const int bc = blockIdx.y, b = b0 + bc;
  if (tid < HIDh) {
    const int c = tid, g = c >> 3;
    float s = 0.f, q = 0.f;
#pragma unroll
    for (int cc = 0; cc < 8; cc++) {
      s += stats2c[((long)b * HIDh + g * 8 + cc) * STP];
      q += stats2c[((long)b * HIDh + g * 8 + cc) * STP + 1];
    }
    const float cnt = 8.f * NMs;
    const float mu = s / cnt;
    const float var = q / cnt - mu * mu;
    const float A2 = rsqrtf(var + EPSf) * g2[c];
    wA[c] = A2; wB[c] = b2[c] - mu * A2;
  }
  if (tid < HIDh * NHh) {
    const int c = tid >> 3, h = tid & 7;
    wrs[c][h] = Wred[h * HIDh + c];
  }
  __syncthreads();
  const int rsel = lane >> 5, ms = lane & 31;
  const int n = blockIdx.x * 8 + wv * 2 + rsel;
  const unsigned short* xp = x2 + (long)(bc * Nn + n) * HIDh * Mm + ms * 8;
  v2f red[NHh][4] = {};    // m-pairs: [mi] covers m = 2mi, 2mi+1
#pragma unroll
  for (int c = 0; c < HIDh; c++) {
    const uint4 xv = *(const uint4*)&xp[c * Mm];
    const v2f A2 = {wA[c], wA[c]}, B2 = {wB[c], wB[c]};
    v2f xw[4];
    xw[0] = (v2f){bflo(xv.x), bfhi(xv.x)};
    xw[1] = (v2f){bflo(xv.y), bfhi(xv.y)};
    xw[2] = (v2f){bflo(xv.z), bfhi(xv.z)};
    xw[3] = (v2f){bflo(xv.w), bfhi(xv.w)};
#pragma unroll
    for (int mi = 0; mi < 4; mi++) xw[mi] = swish2(xw[mi] * A2 + B2);
#pragma unroll
    for (int h = 0; h < NHh; h++) {
      const float w = wrs[c][h];
      const v2f w2 = {w, w};
#pragma unroll
      for (int mi = 0; mi < 4; mi++) red[h][mi] += w2 * xw[mi];
    }
  }
  v2f s3v = {0.f, 0.f}, q3v = {0.f, 0.f};
#pragma unroll
  for (int h = 0; h < NHh; h++) {
    uint4 st;
    st.x = cvtpk(red[h][0].x, red[h][0].y);
    st.y = cvtpk(red[h][1].x, red[h][1].y);
    st.z = cvtpk(red[h][2].x, red[h][2].y);
    st.w = cvtpk(red[h][3].x, red[h][3].y);
    *(uint4*)&a2[(((long)b * NHh + h) * Nn + n) * Mm + ms * 8] = st;
#pragma unroll
    for (int mi = 0; mi < 4; mi++) {
      s3v += red[h][mi];
      q3v += red[h][mi] * red[h][mi];
    }
  }
  float s3 = s3v.x + s3v.y, q3 = q3v.x + q3v.y;
  s3 = wave_sum(s3); q3 = wave_sum(q3);
  if (lane == 0) { red2s[0][wv] = s3; red2s[1][wv] = q3; }
  __syncthreads();
  if (tid < 2) {
    float t = red2s[tid][0] + red2s[tid][1] + red2s[tid][2] + red2s[tid][3];
    partial3[((long)b * 128 + blockIdx.x) * 2 + tid] = t;
  }
}

// ------------- pv_mfma: gn3 (in-kernel stats3+sv reduce) + PV via MFMA -> oT -------------
__launch_bounds__(256)
__global__ void pv_mfma(const unsigned short* __restrict__ a2, const unsigned short* __restrict__ vb,
                        const float* __restrict__ partial3,
                        const float* __restrict__ g3, const float* __restrict__ b3,
                        float* __restrict__ o)
{
  __shared__ __align__(16) unsigned short Vt[32 * 264];   // [d][m] bf16, +8 pad
  __shared__ float svl[32][9];
  __shared__ float r4s[4];
  const int b = blockIdx.z, h = blockIdx.y, n0 = blockIdx.x * 128;
  const int tid = threadIdx.x;
  const int lane = tid & 63, wv = tid >> 6;
  const int l15 = lane & 15, l4 = lane >> 4;
  // stage V^T (bf16 copy): vb is [m][d]
  {
    const unsigned short* vp = vb + ((long)b * NHh + h) * Mm * HDd;
#pragma unroll
    for (int u = 0; u < 32; u++) {
      const int idx = tid + u * 256;
      const int m = idx >> 5, d = idx & 31;
      Vt[d * 264 + m] = vp[idx];
    }
  }
  // stats3 reduce: waves 0,1 cover sum halves; waves 2,3 sumsq halves
  float pv_;
  {
    const int half = tid >> 7, i = tid & 127;
    pv_ = partial3[((long)b * 128 + i) * 2 + half];
  }
  __syncthreads();   // Vt staged
  // sv partials: thread (d = tid&31, seg = tid>>5) sums 32 m's from LDS
  {
    const int d = tid & 31, seg = tid >> 5;
    float s = 0.f;
#pragma unroll
    for (int mm = 0; mm < 32; mm++) s += bfup(Vt[d * 264 + seg * 32 + mm]);
    svl[d][seg] = s;
  }
  {
    const float w = wave_sum(pv_);
    if (lane == 0) r4s[wv] = w;
  }
  __syncthreads();
  if (tid < 32) {
    float t = 0.f;
#pragma unroll
    for (int seg = 0; seg < 8; seg++) t += svl[tid][seg];
    svl[tid][0] = t;
  }
  __syncthreads();
  const float cnt = (float)(NHh * NMs);
  const float mu = (r4s[0] + r4s[1]) / cnt;
  const float var = (r4s[2] + r4s[3]) / cnt - mu * mu;
  const float r3 = rsqrtf(var + EPSf);
  const float alpha = r3 * g3[h];
  const float beta = b3[h] - mu * alpha;

  const unsigned short* ap = a2 + (((long)b * NHh + h) * Nn + n0) * Mm;
  f4v acc[2][2] = {};   // [fm: d-tile][fn: n-tile]
#pragma unroll 2
  for (int k0 = 0; k0 < Mm; k0 += 32) {
    bf8v af[2], bf[2];
#pragma unroll
    for (int fm = 0; fm < 2; fm++)   // A = V^T: m-index = d
      af[fm] = *(const bf8v*)&Vt[(fm * 16 + l15) * 264 + k0 + l4 * 8];
#pragma unroll
    for (int fn = 0; fn < 2; fn++)   // B = a2^T: n-index = attn row
      bf[fn] = *(const bf8v*)&ap[(long)(wv * 32 + fn * 16 + l15) * Mm + k0 + l4 * 8];
#pragma unroll
    for (int fm = 0; fm < 2; fm++)
#pragma unroll
      for (int fn = 0; fn < 2; fn++)
        acc[fm][fn] = __builtin_amdgcn_mfma_f32_16x16x32_bf16(af[fm], bf[fn], acc[fm][fn], 0, 0, 0);
  }
#pragma unroll
  for (int fm = 0; fm < 2; fm++) {
#pragma unroll
    for (int r = 0; r < 4; r++) {
      const int d = fm * 16 + l4 * 4 + r;
      const float bv = beta * svl[d][0];
      float* op = o + ((long)b * Cc + h * HDd + d) * Nn + n0 + wv * 32 + l15;
#pragma unroll
      for (int fn = 0; fn < 2; fn++)
        op[fn * 16] = fmaf(alpha, acc[fm][fn][r], bv);   // 16 lanes -> 64 B contiguous
    }
  }
}

extern "C" void kernel_launch(void* const* d_in, const int* in_sizes, int n_in,
                              void* d_out, int out_size, void* d_ws, size_t ws_size,
                              hipStream_t stream) {
  const float* q    = (const float*)d_in[0];
  const float* kv   = (const float*)d_in[1];
  const float* Wq   = (const float*)d_in[2];
  const float* Wkv  = (const float*)d_in[3];
  const float* Wp   = (const float*)d_in[4];
  const float* bp   = (const float*)d_in[5];
  const float* rpb  = (const float*)d_in[6];
  const float* Wexp = (const float*)d_in[7];
  const float* g1   = (const float*)d_in[8];
  const float* b1   = (const float*)d_in[9];
  const float* Wdw  = (const float*)d_in[10];
  const float* g2   = (const float*)d_in[11];
  const float* b2   = (const float*)d_in[12];
  const float* Wred = (const float*)d_in[13];
  const float* g3   = (const float*)d_in[14];
  const float* b3   = (const float*)d_in[15];
  float* out = (float*)d_out;

  // runtime chunk selection: CHUNK=16 -> one DLA launch pair (4 blocks/CU queue
  // depth in pass_b) if the workspace holds the full 16-batch x2 buffer.
  const size_t baseF = (size_t)Bb * NHh * NMs            // attnf + a2f (bf16 halves)
                     + (size_t)Bb * NHh * Mm * HDd * 2   // kbuf + vbuf
                     + (size_t)Bb * 36 * STP + (size_t)Bb * HIDh * STP
                     + (size_t)Bb * 128 * 2;
  const size_t big16 = (size_t)16 * HIDh * NMs / 2;
  const int chunk = (ws_size >= (baseF + big16) * sizeof(float)) ? 16 : 8;
  const size_t bigF = (size_t)chunk * HIDh * NMs / 2;

  float* ws = (float*)d_ws;
  size_t off = 0;
  auto alloc = [&](size_t n) { float* p = ws + off; off += n; return p; };
  float* attnf   = alloc((size_t)Bb * NHh * NMs / 2);      // 67.1 MB (bf16)
  float* a2f     = alloc((size_t)Bb * NHh * NMs / 2);      // 67.1 MB (bf16)
  float* big     = alloc(bigF);                            // qhT -> x2 -> oT
  float* kbuf    = alloc((size_t)Bb * NHh * Mm * HDd);     // bf16 (half used)
  float* vbuf    = alloc((size_t)Bb * NHh * Mm * HDd);     // bf16 (half used)
  float* G       = alloc((size_t)Bb * 36 * STP);           // line-spread
  float* stats2c = alloc((size_t)Bb * HIDh * STP);         // line-spread
  float* partial3= alloc((size_t)Bb * 128 * 2);            // fully overwritten, no memset
  unsigned short* attn = (unsigned short*)attnf;
  unsigned short* a2 = (unsigned short*)a2f;
  unsigned short* kb16 = (unsigned short*)kbuf;
  unsigned short* vb16 = (unsigned short*)vbuf;
  float* qhT = big;                           // dead after attn_softmax
  unsigned short* x2 = (unsigned short*)big;  // alive during DLA chunk loop
  float* oT = big;                            // alive after last pass C

  // zero only the atomic-accumulated buffers (G | stats2c are contiguous)
  hipMemsetAsync(G, 0, (size_t)(Bb * 36 * STP + Bb * HIDh * STP) * sizeof(float), stream);

  // q-projection: O[b,j,i] = sum_k Wq[j,k] * q[b,k,i]  (MFMA bf16)
  gemm_mfma<0><<<dim3(Nn / 64, Cc / 64, Bb), 256, 0, stream>>>(q, Wq, nullptr, qhT, nullptr, Nn);
  // kv-projection: scatter bf16 into kbuf/vbuf [b,h,m,d]  (MFMA bf16)
  gemm_mfma<1><<<dim3(Mm / 64, 512 / 64, Bb), 256, 0, stream>>>(kv, Wkv, nullptr, kbuf, vbuf, Mm);
  attn_softmax<<<dim3(Nn / 64, NHh, Bb), 256, 0, stream>>>(qhT, kb16, rpb, attn);
  gram_stats<<<dim3(NMs / 4096, Bb), 256, 0, stream>>>(attn, G);

  for (int b0 = 0; b0 < Bb; b0 += chunk) {
    dla_pass_b<<<dim3(Nn / TTB, chunk), 768, 0, stream>>>(
        attn, Wexp, g1, b1, G, Wdw, x2, stats2c, b0);
    dla_pass_c<<<dim3(Nn / 8, chunk), 256, 0, stream>>>(
        x2, g2, b2, stats2c, Wred, a2, partial3, b0);
  }

  pv_mfma<<<dim3(Nn / 128, NHh, Bb), 256, 0, stream>>>(a2, vb16, partial3, g3, b3, oT);
  // out-projection: out[b,j,i] = sum_k Wp[j,k] * oT[b,k,i] + bp[j]  (MFMA bf16)
  gemm_mfma<2><<<dim3(Nn / 64, Cc / 64, Bb), 256, 0, stream>>>(oT, Wp, bp, out, nullptr, Nn);
}

// Round 12
// 368.171 us; speedup vs baseline: 1.0100x; 1.0100x over previous
//
#include <hip/hip_runtime.h>
#include <math.h>

#define Bb 16
#define Cc 256
#define Nn 1024
#define Mm 256
#define NHh 8
#define HDd 32
#define HIDh 24
#define NMs (Nn*Mm)
#define TTB 16
#define CHUNK 8
#define EPSf 1e-5f
#define SCALEf 0.17677669529663687f   // 1/sqrt(32)
#define STP 32   // stats padding stride (floats) = 128B cacheline

typedef float v2f __attribute__((ext_vector_type(2)));
typedef __attribute__((ext_vector_type(8))) short bf8v;   // 8 bf16 (4 VGPRs)
typedef __attribute__((ext_vector_type(4))) float f4v;

__device__ __forceinline__ float wave_sum(float v){
#pragma unroll
  for (int off=32; off; off>>=1) v += __shfl_xor(v, off, 64);
  return v;
}
// fast sigmoid: v_exp + v_rcp (rel err ~2^-22, far below bf16 storage error)
__device__ __forceinline__ float sigm_(float x){ return __builtin_amdgcn_rcpf(1.f + __expf(-x)); }
__device__ __forceinline__ float swish_(float x){ return x * sigm_(x); }
__device__ __forceinline__ v2f swish2(v2f x){
  v2f r;
  r.x = x.x * sigm_(x.x);
  r.y = x.y * sigm_(x.y);
  return r;
}
__device__ __forceinline__ unsigned short f2bf(float f){
  unsigned u = __float_as_uint(f);
  u += 0x7fffu + ((u >> 16) & 1u);          // round-to-nearest-even
  return (unsigned short)(u >> 16);
}
// packed f32x2 -> bf16x2 convert (RNE, single instruction) — lo in [15:0], hi in [31:16]
__device__ __forceinline__ unsigned cvtpk(float lo, float hi){
  unsigned r;
  asm("v_cvt_pk_bf16_f32 %0, %1, %2" : "=v"(r) : "v"(lo), "v"(hi));
  return r;
}
__device__ __forceinline__ float bfup(unsigned short s){ return __uint_as_float(((unsigned)s) << 16); }
__device__ __forceinline__ float bflo(unsigned u){ return __uint_as_float(u << 16); }
__device__ __forceinline__ float bfhi(unsigned u){ return __uint_as_float(u & 0xffff0000u); }
// async global->LDS DMA, 16 B per lane; LDS dest is wave-uniform base + lane*16
__device__ __forceinline__ void gload_lds16(const void* g, void* l){
  __builtin_amdgcn_global_load_lds(
      (const __attribute__((address_space(1))) unsigned int*)g,
      (__attribute__((address_space(3))) unsigned int*)l, 16, 0, 0);
}

// ------------- MFMA GEMM: O[b,j,i] = sum_k W[j,k]*A[b,k,i] --------------
// MODE 0: BF16 store O1[(b*Cc+j)*Nn+i]                (q-projection -> qhT bf16)
// MODE 1: scatter j->(two,h,d), store BF16 to O1/O2   (kv-projection, Isize=Mm)
// MODE 2: f32 store + bias                            (out-projection)
// ABF  : A is bf16 (out-projection reads bf16 oT)
// Rounding note: MODE0/ABF move the SAME RNE bf16 rounding across the HBM hop —
// downstream values are bit-identical to the f32-store variant.
// 64x64 tile, 4 waves of 32x32. Fragment layouts (m89/m91, proven R6-R11):
//   A/B frag: idx=l&15, k=(l>>4)*8+e | D: col=l&15, row=(l>>4)*4+r
template<int MODE, int ABF>
__launch_bounds__(256)
__global__ void gemm_mfma(const float* __restrict__ A,   // [b][k][i], i-stride 1, k-stride Isize
                          const float* __restrict__ W,   // [j][k], k-stride Cc
                          const float* __restrict__ bias,
                          float* __restrict__ O1, float* __restrict__ O2, int Isize)
{
  __shared__ __align__(16) unsigned short Wt[64 * 40];   // [j][k0..31] +8 pad
  __shared__ __align__(16) unsigned short At[64 * 40];   // [i][k0..31] +8 pad (transposed A)
  const int b = blockIdx.z;
  const int i0 = blockIdx.x * 64;
  const int j0 = blockIdx.y * 64;
  const int tid = threadIdx.x;
  const int lane = tid & 63, wv = tid >> 6;
  const int wj = (wv >> 1) * 32, wi = (wv & 1) * 32;
  const int l15 = lane & 15, l4 = lane >> 4;

  const int sj = tid >> 2, skh = (tid & 3) * 8;    // W staging: row j, 8-k block
  const int si = tid & 63, skb = (tid >> 6) * 8;   // A staging: col i, 8-k block

  f4v acc[2][2] = {};
  for (int k0 = 0; k0 < Cc; k0 += 32) {
    float wreg[8];
    {
      const float* wp = W + (long)(j0 + sj) * Cc + k0 + skh;
      *(f4v*)&wreg[0] = *(const f4v*)&wp[0];
      *(f4v*)&wreg[4] = *(const f4v*)&wp[4];
    }
    float areg[8];
    unsigned short areg16[8];
    if constexpr (ABF) {
      const unsigned short* ap = (const unsigned short*)A
          + (long)b * Cc * Isize + (long)(k0 + skb) * Isize + i0 + si;
#pragma unroll
      for (int e = 0; e < 8; e++) areg16[e] = ap[(long)e * Isize];   // coalesced across lanes
    } else {
      const float* ap = A + (long)b * Cc * Isize + (long)(k0 + skb) * Isize + i0 + si;
#pragma unroll
      for (int e = 0; e < 8; e++) areg[e] = ap[(long)e * Isize];     // coalesced across lanes
    }
    __syncthreads();   // previous compute done reading LDS
    {
      unsigned pk[4];
#pragma unroll
      for (int t = 0; t < 4; t++) pk[t] = cvtpk(wreg[2*t], wreg[2*t+1]);
      *(uint4*)&Wt[sj*40 + skh] = make_uint4(pk[0], pk[1], pk[2], pk[3]);
      if constexpr (ABF) {
#pragma unroll
        for (int t = 0; t < 4; t++)
          pk[t] = (unsigned)areg16[2*t] | ((unsigned)areg16[2*t+1] << 16);
      } else {
#pragma unroll
        for (int t = 0; t < 4; t++) pk[t] = cvtpk(areg[2*t], areg[2*t+1]);
      }
      *(uint4*)&At[si*40 + skb] = make_uint4(pk[0], pk[1], pk[2], pk[3]);
    }
    __syncthreads();   // tile staged
    bf8v af[2], bf[2];
#pragma unroll
    for (int fm = 0; fm < 2; fm++)
      af[fm] = *(const bf8v*)&Wt[(wj + fm*16 + l15)*40 + l4*8];
#pragma unroll
    for (int fn = 0; fn < 2; fn++)
      bf[fn] = *(const bf8v*)&At[(wi + fn*16 + l15)*40 + l4*8];
#pragma unroll
    for (int fm = 0; fm < 2; fm++)
#pragma unroll
      for (int fn = 0; fn < 2; fn++)
        acc[fm][fn] = __builtin_amdgcn_mfma_f32_16x16x32_bf16(af[fm], bf[fn], acc[fm][fn], 0, 0, 0);
  }
  // ---- epilogue: D col=l&15 (i), row=(l>>4)*4+r (j) ----
#pragma unroll
  for (int fm = 0; fm < 2; fm++) {
    const int jb = j0 + wj + fm*16 + l4*4;   // j for r=0
    f4v bv = {0.f, 0.f, 0.f, 0.f};
    if (MODE == 2) bv = *(const f4v*)&bias[jb];
#pragma unroll
    for (int fn = 0; fn < 2; fn++) {
      const int ii = i0 + wi + fn*16 + l15;
      if (MODE == 1) {
        // bf16 store: d0..d0+3 consecutive over r, within one head (d0 mult of 4)
        const int two = jb >> 8, jj = jb & 255;
        const int h = jj >> 5, d0 = jj & 31;
        unsigned short* p = (unsigned short*)(two ? O2 : O1)
                          + (((long)b * NHh + h) * Mm + ii) * HDd + d0;
        *(uint2*)p = make_uint2(cvtpk(acc[fm][fn][0], acc[fm][fn][1]),
                                cvtpk(acc[fm][fn][2], acc[fm][fn][3]));
      } else if (MODE == 0) {
        unsigned short* op = (unsigned short*)O1 + ((long)b * Cc + jb) * (long)Isize + ii;
#pragma unroll
        for (int r = 0; r < 4; r++)
          op[(long)r * Isize] = f2bf(acc[fm][fn][r]);
      } else {
        float* op = O1 + ((long)b * Cc + jb) * (long)Isize + ii;
#pragma unroll
        for (int r = 0; r < 4; r++)
          op[(long)r * Isize] = acc[fm][fn][r] + bv[r];
      }
    }
  }
}

// ------------- scores + softmax -> attn (bf16), QK^T via MFMA (proven R8-R11) -------------
// Q and K both arrive bf16 -> staging is pure copies/packs, no cvt.
__launch_bounds__(256)
__global__ void attn_softmax(const unsigned short* __restrict__ qhT,
                             const unsigned short* __restrict__ kb,
                             const float* __restrict__ rpb, unsigned short* __restrict__ attn)
{
  __shared__ __align__(16) unsigned short Kt[Mm * 40];   // [m][d] bf16 +8 pad (20.5 KB)
  __shared__ __align__(16) unsigned short Qt[64 * 40];   // [n][d] bf16 +8 pad (5.1 KB)
  const int b = blockIdx.z, h = blockIdx.y, n0 = blockIdx.x * 64;
  const int tid = threadIdx.x;
  const int lane = tid & 63, wv = tid >> 6;
  const int l15 = lane & 15, l4 = lane >> 4;
  // stage K (bf16 copy): 256 rows x 32 d = 1024 uint4
  {
    const unsigned short* kp = kb + ((long)b * NHh + h) * Mm * HDd;
#pragma unroll
    for (int u = 0; u < 4; u++) {
      const int f = tid + u * 256;
      const int m = f >> 2, q8 = (f & 3) * 8;
      *(uint4*)&Kt[m * 40 + q8] = *(const uint4*)&kp[m * HDd + q8];
    }
  }
  // stage Q^T (bf16): qhT is [d][n]; each thread covers 2 d per n
  {
    const unsigned short* qp = qhT + ((long)b * NHh + h) * HDd * Nn + n0;
#pragma unroll
    for (int u = 0; u < 4; u++) {
      const int f = tid + u * 256;
      const int n = f & 63, d2 = (f >> 6) * 2;
      const unsigned q0 = qp[(long)d2 * Nn + n];
      const unsigned q1 = qp[(long)(d2 + 1) * Nn + n];
      *(unsigned*)&Qt[n * 40 + d2] = q0 | (q1 << 16);
    }
  }
  __syncthreads();
  const bf8v qf = *(const bf8v*)&Qt[(wv * 16 + l15) * 40 + l4 * 8];
  f4v S[16];
#pragma unroll
  for (int mt = 0; mt < 16; mt++) {
    const bf8v kf = *(const bf8v*)&Kt[(mt * 16 + l15) * 40 + l4 * 8];
    f4v z = {0.f, 0.f, 0.f, 0.f};
    S[mt] = __builtin_amdgcn_mfma_f32_16x16x32_bf16(kf, qf, z, 0, 0, 0);
  }
  // lane holds S[n][m = mt*16 + l4*4 + r] for fixed n = n0 + wv*16 + l15
  const int n = n0 + wv * 16 + l15;
  const float* rp = rpb + (long)n * Mm;
  float mx = -1e30f;
#pragma unroll
  for (int mt = 0; mt < 16; mt++) {
    const f4v r4 = *(const f4v*)&rp[mt * 16 + l4 * 4];
    S[mt][0] = fmaf(S[mt][0], SCALEf, r4.x);
    S[mt][1] = fmaf(S[mt][1], SCALEf, r4.y);
    S[mt][2] = fmaf(S[mt][2], SCALEf, r4.z);
    S[mt][3] = fmaf(S[mt][3], SCALEf, r4.w);
    mx = fmaxf(mx, fmaxf(fmaxf(S[mt][0], S[mt][1]), fmaxf(S[mt][2], S[mt][3])));
  }
  mx = fmaxf(mx, __shfl_xor(mx, 16, 64));
  mx = fmaxf(mx, __shfl_xor(mx, 32, 64));
  float sum = 0.f;
#pragma unroll
  for (int mt = 0; mt < 16; mt++) {
    S[mt][0] = __expf(S[mt][0] - mx);
    S[mt][1] = __expf(S[mt][1] - mx);
    S[mt][2] = __expf(S[mt][2] - mx);
    S[mt][3] = __expf(S[mt][3] - mx);
    sum += (S[mt][0] + S[mt][1]) + (S[mt][2] + S[mt][3]);
  }
  sum += __shfl_xor(sum, 16, 64);
  sum += __shfl_xor(sum, 32, 64);
  const float inv = __builtin_amdgcn_rcpf(sum);
  unsigned short* ap = attn + (((long)b * NHh + h) * Nn + n) * Mm;
#pragma unroll
  for (int mt = 0; mt < 16; mt++) {
    const unsigned p0 = cvtpk(S[mt][0] * inv, S[mt][1] * inv);
    const unsigned p1 = cvtpk(S[mt][2] * inv, S[mt][3] * inv);
    *(uint2*)&ap[mt * 16 + l4 * 4] = make_uint2(p0, p1);
  }
}

// ------------- Gram matrix G[b][36*STP] (line-spread atomics, R22 2-chunk) -------------
__launch_bounds__(256)
__global__ void gram_stats(const unsigned short* __restrict__ attn, float* __restrict__ G)
{
  __shared__ float red[36][4];
  const int b = blockIdx.y, tid = threadIdx.x;
  const unsigned short* ap = attn + (long)b * NHh * NMs + (long)blockIdx.x * 4096 + tid * 8;
  float g[36] = {};
#pragma unroll
  for (int half = 0; half < 2; half++) {
    const unsigned short* app = ap + half * 2048;
    float a[8][8];
#pragma unroll
    for (int h = 0; h < 8; h++) {
      const uint4 v = *(const uint4*)&app[(long)h * NMs];
      a[h][0] = bflo(v.x); a[h][1] = bfhi(v.x); a[h][2] = bflo(v.y); a[h][3] = bfhi(v.y);
      a[h][4] = bflo(v.z); a[h][5] = bfhi(v.z); a[h][6] = bflo(v.w); a[h][7] = bfhi(v.w);
    }
    int t = 0;
#pragma unroll
    for (int i = 0; i < 8; i++)
#pragma unroll
      for (int j = i; j < 8; j++, t++) {
        float s = 0.f;
#pragma unroll
        for (int m = 0; m < 8; m++) s = fmaf(a[i][m], a[j][m], s);
        g[t] += s;
      }
  }
  const int lane = tid & 63, wid = tid >> 6;
#pragma unroll
  for (int t2 = 0; t2 < 36; t2++) {
    const float s = wave_sum(g[t2]);
    if (lane == 0) red[t2][wid] = s;
  }
  __syncthreads();
  if (tid < 36)
    atomicAdd(&G[((long)b * 36 + tid) * STP],
              red[tid][0] + red[tid][1] + red[tid][2] + red[tid][3]);
}

// ------------- pass B: expand+gn1(from G)+swish -> conv3x3 -> x2(bf16) + gn2 stats ----
// R18/R7 inner loop (proven). R23: PHASE-SPLIT staging — stage rows 0-9, barrier,
// issue rows 10-17 AFTER barrier-1 (so its vmcnt(0) doesn't drain them), compute
// r=-1..8 while phase-2 DMA flies, conditional barrier at r==9 (its per-wave
// vmcnt(0) waits only on own DMAs; barrier syncs all waves -> all planes staged).
// Hides the launch-start DMA burst (both resident blocks burst at t=0) under compute.
__launch_bounds__(768, 6)
__global__ void dla_pass_b(const unsigned short* __restrict__ attn,
                           const float* __restrict__ Wexp,
                           const float* __restrict__ g1, const float* __restrict__ b1,
                           const float* __restrict__ G, const float* __restrict__ Wdw,
                           unsigned short* __restrict__ x2, float* __restrict__ stats2c, int b0)
{
  __shared__ __align__(16) unsigned short sl[(TTB + 2) * NHh * Mm];  // 73728 B
  const int tid = threadIdx.x;
  const int wv = tid >> 6, lane = tid & 63;   // wv 0..11
  const int bc = blockIdx.y, b = b0 + bc;
  const int n0 = blockIdx.x * TTB;
  const int c0 = wv * 2;        // channel pair owned by this wave
  const int g = wv >> 2;        // GN group (channels 0-7 / 8-15 / 16-23)

  const unsigned short* abase = attn + (long)b * NHh * NMs;
  const int q_lo = lane >> 5;         // which plane of the pair this lane fills
  const int m0 = (lane & 31) * 8;     // ushort offset within the 512 B plane
  // ---- phase-1 staging: rows 0..9 = planes 0..79 = pairs 0..39 ----
#pragma unroll
  for (int i = 0; i < 4; i++) {
    const int pr = wv + i * 12;
    if (pr < 40) {
      const int pp = pr * 2;
      const int row = pp >> 3;
      const int nn = n0 - 1 + row;
      if (nn >= 0 && nn < Nn) {
        const int h = (pp + q_lo) & 7;
        gload_lds16(abase + (long)h * NMs + (long)nn * Mm + m0, &sl[pp * Mm]);
      }
    }
  }

  // gn1 stats from Gram matrix (mean exact: softmax rows sum to 1)
  float mu, rs;
  {
    const float* Gb = G + (long)b * 36 * STP;
    float sum = 0.f, sumsq = 0.f;
    for (int c = g * 8; c < g * 8 + 8; c++) {
      float w[8];
#pragma unroll
      for (int h = 0; h < 8; h++) w[h] = Wexp[c * 8 + h];
      float wsu = 0.f;
#pragma unroll
      for (int h = 0; h < 8; h++) wsu += w[h];
      sum += wsu;
      float s2 = 0.f;
      int t = 0;
#pragma unroll
      for (int i = 0; i < 8; i++)
#pragma unroll
        for (int j = i; j < 8; j++, t++) {
          const float f = (i == j) ? 1.f : 2.f;
          s2 = fmaf(f * w[i] * w[j], Gb[t * STP], s2);
        }
      sumsq += s2;
    }
    const float cnt = 8.f * NMs;
    mu = sum * ((float)Nn / cnt);
    const float var = sumsq / cnt - mu * mu;
    rs = rsqrtf(var + EPSf);
  }
  // channel-pair (v2f) weights: lane .x -> c0, lane .y -> c0+1 (wave-uniform)
  v2f we2[8], wd2[9], B12;
  {
    const float A10 = rs * g1[c0], A11 = rs * g1[c0 + 1];
    B12.x = b1[c0] - mu * A10;
    B12.y = b1[c0 + 1] - mu * A11;
#pragma unroll
    for (int h = 0; h < NHh; h++) {
      we2[h].x = Wexp[c0 * NHh + h] * A10;
      we2[h].y = Wexp[(c0 + 1) * NHh + h] * A11;
    }
#pragma unroll
    for (int k = 0; k < 9; k++) {
      wd2[k].x = Wdw[c0 * 9 + k];
      wd2[k].y = Wdw[(c0 + 1) * 9 + k];
    }
  }
  __syncthreads();   // barrier 1: phase-1 planes staged (drains only phase-1 DMAs)

  // ---- phase-2 staging: rows 10..17 = planes 80..143 = pairs 40..71 ----
  // issued AFTER barrier-1 so it overlaps phase-1 compute; drained by barrier-2.
#pragma unroll
  for (int i = 0; i < 3; i++) {
    const int pr = 40 + wv + i * 12;
    if (pr < 72) {
      const int pp = pr * 2;
      const int row = pp >> 3;
      const int nn = n0 - 1 + row;
      if (nn >= 0 && nn < Nn) {
        const int h = (pp + q_lo) & 7;
        gload_lds16(abase + (long)h * NMs + (long)nn * Mm + m0, &sl[pp * Mm]);
      }
    }
  }

  v2f s1p[4] = {}, s2p[4] = {};
  v2f smp = {0.f, 0.f}, sqp = {0.f, 0.f};
  for (int r = -1; r <= TTB; r++) {
    if (r == 9) __syncthreads();   // barrier 2: phase-2 planes staged (mostly hidden)
    const int nn = n0 + r;
    const bool rowv = (nn >= 0 && nn < Nn);
    v2f xp[4];
    if (rowv) {
#pragma unroll
      for (int mi = 0; mi < 4; mi++) xp[mi] = B12;
      const unsigned short* sp = &sl[(r + 1) * NHh * Mm + lane * 4];
#pragma unroll
      for (int h = 0; h < NHh; h++) {
        const ushort4 v = *(const ushort4*)&sp[h * Mm];   // ds_read_b64, 2-way alias
        xp[0] += we2[h] * bfup(v.x);
        xp[1] += we2[h] * bfup(v.y);
        xp[2] += we2[h] * bfup(v.z);
        xp[3] += we2[h] * bfup(v.w);
      }
#pragma unroll
      for (int mi = 0; mi < 4; mi++) xp[mi] = swish2(xp[mi]);
    } else {
#pragma unroll
      for (int mi = 0; mi < 4; mi++) xp[mi] = (v2f){0.f, 0.f};
    }
    // horizontal halo via shuffles (per component; shfl is 32-bit)
    v2f xl, xr;
    xl.x = __shfl_up(xp[3].x, 1);  xl.y = __shfl_up(xp[3].y, 1);
    xr.x = __shfl_down(xp[0].x, 1); xr.y = __shfl_down(xp[0].y, 1);
    if (lane == 0)  { xl = (v2f){0.f, 0.f}; }
    if (lane == 63) { xr = (v2f){0.f, 0.f}; }
    const v2f L[4] = {xl, xp[0], xp[1], xp[2]};
    const v2f R[4] = {xp[1], xp[2], xp[3], xr};
    v2f y[4];
#pragma unroll
    for (int mi = 0; mi < 4; mi++) {
      const v2f u0 = wd2[0] * L[mi] + wd2[1] * xp[mi] + wd2[2] * R[mi];
      const v2f u1 = wd2[3] * L[mi] + wd2[4] * xp[mi] + wd2[5] * R[mi];
      const v2f u2 = wd2[6] * L[mi] + wd2[7] * xp[mi] + wd2[8] * R[mi];
      y[mi] = s2p[mi] + u2;
      s2p[mi] = s1p[mi] + u1;
      s1p[mi] = u0;
    }
    if (r >= 1) {
#pragma unroll
      for (int mi = 0; mi < 4; mi++) {
        smp += y[mi];
        sqp += y[mi] * y[mi];
      }
      const int nw = n0 + r - 1;
      const unsigned w0 = cvtpk(y[0].x, y[1].x), w1 = cvtpk(y[2].x, y[3].x);
      const unsigned w2 = cvtpk(y[0].y, y[1].y), w3 = cvtpk(y[2].y, y[3].y);
      unsigned short* xq = x2 + ((long)(bc * Nn + nw) * HIDh + c0) * Mm + lane * 4;
      *(uint2*)xq        = make_uint2(w0, w1);   // channel c0
      *(uint2*)(xq + Mm) = make_uint2(w2, w3);   // channel c0+1
    }
  }
  {
    const float vs0 = wave_sum(smp.x), vq0 = wave_sum(sqp.x);
    const float vs1 = wave_sum(smp.y), vq1 = wave_sum(sqp.y);
    if (lane == 0) {
      atomicAdd(&stats2c[((long)b * HIDh + c0) * STP], vs0);
      atomicAdd(&stats2c[((long)b * HIDh + c0) * STP + 1], vq0);
      atomicAdd(&stats2c[((long)b * HIDh + c0 + 1) * STP], vs1);
      atomicAdd(&stats2c[((long)b * HIDh + c0 + 1) * STP + 1], vq1);
    }
  }
}

// ------------- pass C: gn2+swish + 1x1 reduce -> a2(bf16) + partial gn3 stats -------
// R21 m-pair packed accumulate (proven R10/R11).
__launch_bounds__(256)
__global__ void dla_pass_c(const unsigned short* __restrict__ x2, const float* __restrict__ g2,
                           const float* __restrict__ b2, const float* __restrict__ stats2c,
                           const float* __restrict__ Wred, unsigned short* __restrict__ a2,
                           float* __restrict__ partial3, int b0)
{
  __shared__ float wA[HIDh], wB[HIDh], wrs[HIDh][NHh];
  __shared__ float red2s[2][4];
  const int tid = threadIdx.x;
  const int wv = tid >> 6, lane = tid & 63;
  const int bc = blockIdx.y, b = b0 + bc;
  if (tid < HIDh) {
    const int c = tid, g = c >> 3;
    float s = 0.f, q = 0.f;
#pragma unroll
    for (int cc = 0; cc < 8; cc++) {
      s += stats2c[((long)b * HIDh + g * 8 + cc) * STP];
      q += stats2c[((long)b * HIDh + g * 8 + cc) * STP + 1];
    }
    const float cnt = 8.f * NMs;
    const float mu = s / cnt;
    const float var = q / cnt - mu * mu;
    const float A2 = rsqrtf(var + EPSf) * g2[c];
    wA[c] = A2; wB[c] = b2[c] - mu * A2;
  }
  if (tid < HIDh * NHh) {
    const int c = tid >> 3, h = tid & 7;
    wrs[c][h] = Wred[h * HIDh + c];
  }
  __syncthreads();
  const int rsel = lane >> 5, ms = lane & 31;
  const int n = blockIdx.x * 8 + wv * 2 + rsel;
  const unsigned short* xp = x2 + (long)(bc * Nn + n) * HIDh * Mm + ms * 8;
  v2f red[NHh][4] = {};    // m-pairs: [mi] covers m = 2mi, 2mi+1
#pragma unroll
  for (int c = 0; c < HIDh; c++) {
    const uint4 xv = *(const uint4*)&xp[c * Mm];
    const v2f A2 = {wA[c], wA[c]}, B2 = {wB[c], wB[c]};
    v2f xw[4];
    xw[0] = (v2f){bflo(xv.x), bfhi(xv.x)};
    xw[1] = (v2f){bflo(xv.y), bfhi(xv.y)};
    xw[2] = (v2f){bflo(xv.z), bfhi(xv.z)};
    xw[3] = (v2f){bflo(xv.w), bfhi(xv.w)};
#pragma unroll
    for (int mi = 0; mi < 4; mi++) xw[mi] = swish2(xw[mi] * A2 + B2);
#pragma unroll
    for (int h = 0; h < NHh; h++) {
      const float w = wrs[c][h];
      const v2f w2 = {w, w};
#pragma unroll
      for (int mi = 0; mi < 4; mi++) red[h][mi] += w2 * xw[mi];
    }
  }
  v2f s3v = {0.f, 0.f}, q3v = {0.f, 0.f};
#pragma unroll
  for (int h = 0; h < NHh; h++) {
    uint4 st;
    st.x = cvtpk(red[h][0].x, red[h][0].y);
    st.y = cvtpk(red[h][1].x, red[h][1].y);
    st.z = cvtpk(red[h][2].x, red[h][2].y);
    st.w = cvtpk(red[h][3].x, red[h][3].y);
    *(uint4*)&a2[(((long)b * NHh + h) * Nn + n) * Mm + ms * 8] = st;
#pragma unroll
    for (int mi = 0; mi < 4; mi++) {
      s3v += red[h][mi];
      q3v += red[h][mi] * red[h][mi];
    }
  }
  float s3 = s3v.x + s3v.y, q3 = q3v.x + q3v.y;
  s3 = wave_sum(s3); q3 = wave_sum(q3);
  if (lane == 0) { red2s[0][wv] = s3; red2s[1][wv] = q3; }
  __syncthreads();
  if (tid < 2) {
    float t = red2s[tid][0] + red2s[tid][1] + red2s[tid][2] + red2s[tid][3];
    partial3[((long)b * 128 + blockIdx.x) * 2 + tid] = t;
  }
}

// ------------- pv_mfma: gn3 (in-kernel stats3+sv reduce) + PV via MFMA -> oT (bf16) ----
__launch_bounds__(256)
__global__ void pv_mfma(const unsigned short* __restrict__ a2, const unsigned short* __restrict__ vb,
                        const float* __restrict__ partial3,
                        const float* __restrict__ g3, const float* __restrict__ b3,
                        unsigned short* __restrict__ o)
{
  __shared__ __align__(16) unsigned short Vt[32 * 264];   // [d][m] bf16, +8 pad
  __shared__ float svl[32][9];
  __shared__ float r4s[4];
  const int b = blockIdx.z, h = blockIdx.y, n0 = blockIdx.x * 128;
  const int tid = threadIdx.x;
  const int lane = tid & 63, wv = tid >> 6;
  const int l15 = lane & 15, l4 = lane >> 4;
  // stage V^T (bf16 copy): vb is [m][d]
  {
    const unsigned short* vp = vb + ((long)b * NHh + h) * Mm * HDd;
#pragma unroll
    for (int u = 0; u < 32; u++) {
      const int idx = tid + u * 256;
      const int m = idx >> 5, d = idx & 31;
      Vt[d * 264 + m] = vp[idx];
    }
  }
  // stats3 reduce: waves 0,1 cover sum halves; waves 2,3 sumsq halves
  float pv_;
  {
    const int half = tid >> 7, i = tid & 127;
    pv_ = partial3[((long)b * 128 + i) * 2 + half];
  }
  __syncthreads();   // Vt staged
  // sv partials: thread (d = tid&31, seg = tid>>5) sums 32 m's from LDS
  {
    const int d = tid & 31, seg = tid >> 5;
    float s = 0.f;
#pragma unroll
    for (int mm = 0; mm < 32; mm++) s += bfup(Vt[d * 264 + seg * 32 + mm]);
    svl[d][seg] = s;
  }
  {
    const float w = wave_sum(pv_);
    if (lane == 0) r4s[wv] = w;
  }
  __syncthreads();
  if (tid < 32) {
    float t = 0.f;
#pragma unroll
    for (int seg = 0; seg < 8; seg++) t += svl[tid][seg];
    svl[tid][0] = t;
  }
  __syncthreads();
  const float cnt = (float)(NHh * NMs);
  const float mu = (r4s[0] + r4s[1]) / cnt;
  const float var = (r4s[2] + r4s[3]) / cnt - mu * mu;
  const float r3 = rsqrtf(var + EPSf);
  const float alpha = r3 * g3[h];
  const float beta = b3[h] - mu * alpha;

  const unsigned short* ap = a2 + (((long)b * NHh + h) * Nn + n0) * Mm;
  f4v acc[2][2] = {};   // [fm: d-tile][fn: n-tile]
#pragma unroll 2
  for (int k0 = 0; k0 < Mm; k0 += 32) {
    bf8v af[2], bf[2];
#pragma unroll
    for (int fm = 0; fm < 2; fm++)   // A = V^T: m-index = d
      af[fm] = *(const bf8v*)&Vt[(fm * 16 + l15) * 264 + k0 + l4 * 8];
#pragma unroll
    for (int fn = 0; fn < 2; fn++)   // B = a2^T: n-index = attn row
      bf[fn] = *(const bf8v*)&ap[(long)(wv * 32 + fn * 16 + l15) * Mm + k0 + l4 * 8];
#pragma unroll
    for (int fm = 0; fm < 2; fm++)
#pragma unroll
      for (int fn = 0; fn < 2; fn++)
        acc[fm][fn] = __builtin_amdgcn_mfma_f32_16x16x32_bf16(af[fm], bf[fn], acc[fm][fn], 0, 0, 0);
  }
#pragma unroll
  for (int fm = 0; fm < 2; fm++) {
#pragma unroll
    for (int r = 0; r < 4; r++) {
      const int d = fm * 16 + l4 * 4 + r;
      const float bv = beta * svl[d][0];
      unsigned short* op = o + ((long)b * Cc + h * HDd + d) * Nn + n0 + wv * 32 + l15;
#pragma unroll
      for (int fn = 0; fn < 2; fn++)
        op[fn * 16] = f2bf(fmaf(alpha, acc[fm][fn][r], bv));   // bf16 oT (re-rounded at
                                                               // out-proj staging anyway)
    }
  }
}

extern "C" void kernel_launch(void* const* d_in, const int* in_sizes, int n_in,
                              void* d_out, int out_size, void* d_ws, size_t ws_size,
                              hipStream_t stream) {
  const float* q    = (const float*)d_in[0];
  const float* kv   = (const float*)d_in[1];
  const float* Wq   = (const float*)d_in[2];
  const float* Wkv  = (const float*)d_in[3];
  const float* Wp   = (const float*)d_in[4];
  const float* bp   = (const float*)d_in[5];
  const float* rpb  = (const float*)d_in[6];
  const float* Wexp = (const float*)d_in[7];
  const float* g1   = (const float*)d_in[8];
  const float* b1   = (const float*)d_in[9];
  const float* Wdw  = (const float*)d_in[10];
  const float* g2   = (const float*)d_in[11];
  const float* b2   = (const float*)d_in[12];
  const float* Wred = (const float*)d_in[13];
  const float* g3   = (const float*)d_in[14];
  const float* b3   = (const float*)d_in[15];
  float* out = (float*)d_out;

  float* ws = (float*)d_ws;
  size_t off = 0;
  auto alloc = [&](size_t n) { float* p = ws + off; off += n; return p; };
  float* attnf   = alloc((size_t)Bb * NHh * NMs / 2);      // 67.1 MB (bf16)
  float* a2f     = alloc((size_t)Bb * NHh * NMs / 2);      // 67.1 MB (bf16)
  float* big     = alloc((size_t)CHUNK * HIDh * NMs / 2);  // 100.7 MB: qhT -> x2 -> oT
  float* kbuf    = alloc((size_t)Bb * NHh * Mm * HDd);     // bf16 (half used)
  float* vbuf    = alloc((size_t)Bb * NHh * Mm * HDd);     // bf16 (half used)
  float* G       = alloc((size_t)Bb * 36 * STP);           // line-spread
  float* stats2c = alloc((size_t)Bb * HIDh * STP);         // line-spread
  float* partial3= alloc((size_t)Bb * 128 * 2);            // fully overwritten, no memset
  unsigned short* attn = (unsigned short*)attnf;
  unsigned short* a2 = (unsigned short*)a2f;
  unsigned short* kb16 = (unsigned short*)kbuf;
  unsigned short* vb16 = (unsigned short*)vbuf;
  unsigned short* qhT16 = (unsigned short*)big;  // bf16, dead after attn_softmax
  unsigned short* x2 = (unsigned short*)big;     // alive during DLA chunk loop
  unsigned short* oT16 = (unsigned short*)big;   // bf16, alive after last pass C

  // zero only the atomic-accumulated buffers (G | stats2c are contiguous)
  hipMemsetAsync(G, 0, (size_t)(Bb * 36 * STP + Bb * HIDh * STP) * sizeof(float), stream);

  // q-projection: qhT (bf16) = Wq x q  (MFMA bf16, bf16 store)
  gemm_mfma<0, 0><<<dim3(Nn / 64, Cc / 64, Bb), 256, 0, stream>>>(
      q, Wq, nullptr, (float*)qhT16, nullptr, Nn);
  // kv-projection: scatter bf16 into kbuf/vbuf [b,h,m,d]  (MFMA bf16)
  gemm_mfma<1, 0><<<dim3(Mm / 64, 512 / 64, Bb), 256, 0, stream>>>(
      kv, Wkv, nullptr, kbuf, vbuf, Mm);
  attn_softmax<<<dim3(Nn / 64, NHh, Bb), 256, 0, stream>>>(qhT16, kb16, rpb, attn);
  gram_stats<<<dim3(NMs / 4096, Bb), 256, 0, stream>>>(attn, G);

  for (int b0 = 0; b0 < Bb; b0 += CHUNK) {
    dla_pass_b<<<dim3(Nn / TTB, CHUNK), 768, 0, stream>>>(
        attn, Wexp, g1, b1, G, Wdw, x2, stats2c, b0);
    dla_pass_c<<<dim3(Nn / 8, CHUNK), 256, 0, stream>>>(
        x2, g2, b2, stats2c, Wred, a2, partial3, b0);
  }

  pv_mfma<<<dim3(Nn / 128, NHh, Bb), 256, 0, stream>>>(a2, vb16, partial3, g3, b3, oT16);
  // out-projection: out = Wp x oT + bp  (MFMA bf16, bf16 A input)
  gemm_mfma<2, 1><<<dim3(Nn / 64, Cc / 64, Bb), 256, 0, stream>>>(
      (const float*)oT16, Wp, bp, out, nullptr, Nn);
}

// Round 13
// 362.569 us; speedup vs baseline: 1.0256x; 1.0155x over previous
//
#include <hip/hip_runtime.h>
#include <math.h>

#define Bb 16
#define Cc 256
#define Nn 1024
#define Mm 256
#define NHh 8
#define HDd 32
#define HIDh 24
#define NMs (Nn*Mm)
#define TTB 16
#define CHUNK 8
#define EPSf 1e-5f
#define SCALEf 0.17677669529663687f   // 1/sqrt(32)
#define STP 32   // stats padding stride (floats) = 128B cacheline

typedef float v2f __attribute__((ext_vector_type(2)));
typedef __attribute__((ext_vector_type(8))) short bf8v;   // 8 bf16 (4 VGPRs)
typedef __attribute__((ext_vector_type(4))) float f4v;

__device__ __forceinline__ float wave_sum(float v){
#pragma unroll
  for (int off=32; off; off>>=1) v += __shfl_xor(v, off, 64);
  return v;
}
// ---- forced packed-fp32 math (gfx950 full-rate fp32 is 2-wide packed; the 157 TF
// ---- figure REQUIRES v_pk_*_f32 — scalarized <2 x float> runs at half rate) ----
__device__ __forceinline__ v2f pk_fma(v2f a, v2f b, v2f c){
  v2f d;
  asm("v_pk_fma_f32 %0, %1, %2, %3" : "=v"(d) : "v"(a), "v"(b), "v"(c));
  return d;
}
__device__ __forceinline__ v2f pk_mul(v2f a, v2f b){
  v2f d;
  asm("v_pk_mul_f32 %0, %1, %2" : "=v"(d) : "v"(a), "v"(b));
  return d;
}
__device__ __forceinline__ v2f pk_add(v2f a, v2f b){
  v2f d;
  asm("v_pk_add_f32 %0, %1, %2" : "=v"(d) : "v"(a), "v"(b));
  return d;
}
// fast sigmoid: v_exp + v_rcp (rel err ~2^-22, far below bf16 storage error)
__device__ __forceinline__ float sigm_(float x){ return __builtin_amdgcn_rcpf(1.f + __expf(-x)); }
__device__ __forceinline__ float swish_(float x){ return x * sigm_(x); }
__device__ __forceinline__ v2f swish2(v2f x){
  v2f r;
  r.x = x.x * sigm_(x.x);
  r.y = x.y * sigm_(x.y);
  return r;
}
__device__ __forceinline__ unsigned short f2bf(float f){
  unsigned u = __float_as_uint(f);
  u += 0x7fffu + ((u >> 16) & 1u);          // round-to-nearest-even
  return (unsigned short)(u >> 16);
}
// packed f32x2 -> bf16x2 convert (RNE, single instruction) — lo in [15:0], hi in [31:16]
__device__ __forceinline__ unsigned cvtpk(float lo, float hi){
  unsigned r;
  asm("v_cvt_pk_bf16_f32 %0, %1, %2" : "=v"(r) : "v"(lo), "v"(hi));
  return r;
}
__device__ __forceinline__ float bfup(unsigned short s){ return __uint_as_float(((unsigned)s) << 16); }
__device__ __forceinline__ float bflo(unsigned u){ return __uint_as_float(u << 16); }
__device__ __forceinline__ float bfhi(unsigned u){ return __uint_as_float(u & 0xffff0000u); }
// async global->LDS DMA, 16 B per lane; LDS dest is wave-uniform base + lane*16
__device__ __forceinline__ void gload_lds16(const void* g, void* l){
  __builtin_amdgcn_global_load_lds(
      (const __attribute__((address_space(1))) unsigned int*)g,
      (__attribute__((address_space(3))) unsigned int*)l, 16, 0, 0);
}

// ------------- MFMA GEMM: O[b,j,i] = sum_k W[j,k]*A[b,k,i] --------------
// MODE 0: BF16 store O1[(b*Cc+j)*Nn+i]                (q-projection -> qhT bf16)
// MODE 1: scatter j->(two,h,d), store BF16 to O1/O2   (kv-projection, Isize=Mm)
// MODE 2: f32 store + bias                            (out-projection)
// ABF  : A is bf16 (out-projection reads bf16 oT)
// 64x64 tile, 4 waves of 32x32. Fragment layouts (m89/m91, proven R6-R12):
//   A/B frag: idx=l&15, k=(l>>4)*8+e | D: col=l&15, row=(l>>4)*4+r
template<int MODE, int ABF>
__launch_bounds__(256)
__global__ void gemm_mfma(const float* __restrict__ A,   // [b][k][i], i-stride 1, k-stride Isize
                          const float* __restrict__ W,   // [j][k], k-stride Cc
                          const float* __restrict__ bias,
                          float* __restrict__ O1, float* __restrict__ O2, int Isize)
{
  __shared__ __align__(16) unsigned short Wt[64 * 40];   // [j][k0..31] +8 pad
  __shared__ __align__(16) unsigned short At[64 * 40];   // [i][k0..31] +8 pad (transposed A)
  const int b = blockIdx.z;
  const int i0 = blockIdx.x * 64;
  const int j0 = blockIdx.y * 64;
  const int tid = threadIdx.x;
  const int lane = tid & 63, wv = tid >> 6;
  const int wj = (wv >> 1) * 32, wi = (wv & 1) * 32;
  const int l15 = lane & 15, l4 = lane >> 4;

  const int sj = tid >> 2, skh = (tid & 3) * 8;    // W staging: row j, 8-k block
  const int si = tid & 63, skb = (tid >> 6) * 8;   // A staging: col i, 8-k block

  f4v acc[2][2] = {};
  for (int k0 = 0; k0 < Cc; k0 += 32) {
    float wreg[8];
    {
      const float* wp = W + (long)(j0 + sj) * Cc + k0 + skh;
      *(f4v*)&wreg[0] = *(const f4v*)&wp[0];
      *(f4v*)&wreg[4] = *(const f4v*)&wp[4];
    }
    float areg[8];
    unsigned short areg16[8];
    if constexpr (ABF) {
      const unsigned short* ap = (const unsigned short*)A
          + (long)b * Cc * Isize + (long)(k0 + skb) * Isize + i0 + si;
#pragma unroll
      for (int e = 0; e < 8; e++) areg16[e] = ap[(long)e * Isize];   // coalesced across lanes
    } else {
      const float* ap = A + (long)b * Cc * Isize + (long)(k0 + skb) * Isize + i0 + si;
#pragma unroll
      for (int e = 0; e < 8; e++) areg[e] = ap[(long)e * Isize];     // coalesced across lanes
    }
    __syncthreads();   // previous compute done reading LDS
    {
      unsigned pk[4];
#pragma unroll
      for (int t = 0; t < 4; t++) pk[t] = cvtpk(wreg[2*t], wreg[2*t+1]);
      *(uint4*)&Wt[sj*40 + skh] = make_uint4(pk[0], pk[1], pk[2], pk[3]);
      if constexpr (ABF) {
#pragma unroll
        for (int t = 0; t < 4; t++)
          pk[t] = (unsigned)areg16[2*t] | ((unsigned)areg16[2*t+1] << 16);
      } else {
#pragma unroll
        for (int t = 0; t < 4; t++) pk[t] = cvtpk(areg[2*t], areg[2*t+1]);
      }
      *(uint4*)&At[si*40 + skb] = make_uint4(pk[0], pk[1], pk[2], pk[3]);
    }
    __syncthreads();   // tile staged
    bf8v af[2], bf[2];
#pragma unroll
    for (int fm = 0; fm < 2; fm++)
      af[fm] = *(const bf8v*)&Wt[(wj + fm*16 + l15)*40 + l4*8];
#pragma unroll
    for (int fn = 0; fn < 2; fn++)
      bf[fn] = *(const bf8v*)&At[(wi + fn*16 + l15)*40 + l4*8];
#pragma unroll
    for (int fm = 0; fm < 2; fm++)
#pragma unroll
      for (int fn = 0; fn < 2; fn++)
        acc[fm][fn] = __builtin_amdgcn_mfma_f32_16x16x32_bf16(af[fm], bf[fn], acc[fm][fn], 0, 0, 0);
  }
  // ---- epilogue: D col=l&15 (i), row=(l>>4)*4+r (j) ----
#pragma unroll
  for (int fm = 0; fm < 2; fm++) {
    const int jb = j0 + wj + fm*16 + l4*4;   // j for r=0
    f4v bv = {0.f, 0.f, 0.f, 0.f};
    if (MODE == 2) bv = *(const f4v*)&bias[jb];
#pragma unroll
    for (int fn = 0; fn < 2; fn++) {
      const int ii = i0 + wi + fn*16 + l15;
      if (MODE == 1) {
        // bf16 store: d0..d0+3 consecutive over r, within one head (d0 mult of 4)
        const int two = jb >> 8, jj = jb & 255;
        const int h = jj >> 5, d0 = jj & 31;
        unsigned short* p = (unsigned short*)(two ? O2 : O1)
                          + (((long)b * NHh + h) * Mm + ii) * HDd + d0;
        *(uint2*)p = make_uint2(cvtpk(acc[fm][fn][0], acc[fm][fn][1]),
                                cvtpk(acc[fm][fn][2], acc[fm][fn][3]));
      } else if (MODE == 0) {
        unsigned short* op = (unsigned short*)O1 + ((long)b * Cc + jb) * (long)Isize + ii;
#pragma unroll
        for (int r = 0; r < 4; r++)
          op[(long)r * Isize] = f2bf(acc[fm][fn][r]);
      } else {
        float* op = O1 + ((long)b * Cc + jb) * (long)Isize + ii;
#pragma unroll
        for (int r = 0; r < 4; r++)
          op[(long)r * Isize] = acc[fm][fn][r] + bv[r];
      }
    }
  }
}

// ------------- scores + softmax -> attn (bf16), QK^T via MFMA (proven R8-R12) -------------
__launch_bounds__(256)
__global__ void attn_softmax(const unsigned short* __restrict__ qhT,
                             const unsigned short* __restrict__ kb,
                             const float* __restrict__ rpb, unsigned short* __restrict__ attn)
{
  __shared__ __align__(16) unsigned short Kt[Mm * 40];   // [m][d] bf16 +8 pad (20.5 KB)
  __shared__ __align__(16) unsigned short Qt[64 * 40];   // [n][d] bf16 +8 pad (5.1 KB)
  const int b = blockIdx.z, h = blockIdx.y, n0 = blockIdx.x * 64;
  const int tid = threadIdx.x;
  const int lane = tid & 63, wv = tid >> 6;
  const int l15 = lane & 15, l4 = lane >> 4;
  // stage K (bf16 copy): 256 rows x 32 d = 1024 uint4
  {
    const unsigned short* kp = kb + ((long)b * NHh + h) * Mm * HDd;
#pragma unroll
    for (int u = 0; u < 4; u++) {
      const int f = tid + u * 256;
      const int m = f >> 2, q8 = (f & 3) * 8;
      *(uint4*)&Kt[m * 40 + q8] = *(const uint4*)&kp[m * HDd + q8];
    }
  }
  // stage Q^T (bf16): qhT is [d][n]; each thread covers 2 d per n
  {
    const unsigned short* qp = qhT + ((long)b * NHh + h) * HDd * Nn + n0;
#pragma unroll
    for (int u = 0; u < 4; u++) {
      const int f = tid + u * 256;
      const int n = f & 63, d2 = (f >> 6) * 2;
      const unsigned q0 = qp[(long)d2 * Nn + n];
      const unsigned q1 = qp[(long)(d2 + 1) * Nn + n];
      *(unsigned*)&Qt[n * 40 + d2] = q0 | (q1 << 16);
    }
  }
  __syncthreads();
  const bf8v qf = *(const bf8v*)&Qt[(wv * 16 + l15) * 40 + l4 * 8];
  f4v S[16];
#pragma unroll
  for (int mt = 0; mt < 16; mt++) {
    const bf8v kf = *(const bf8v*)&Kt[(mt * 16 + l15) * 40 + l4 * 8];
    f4v z = {0.f, 0.f, 0.f, 0.f};
    S[mt] = __builtin_amdgcn_mfma_f32_16x16x32_bf16(kf, qf, z, 0, 0, 0);
  }
  // lane holds S[n][m = mt*16 + l4*4 + r] for fixed n = n0 + wv*16 + l15
  const int n = n0 + wv * 16 + l15;
  const float* rp = rpb + (long)n * Mm;
  float mx = -1e30f;
#pragma unroll
  for (int mt = 0; mt < 16; mt++) {
    const f4v r4 = *(const f4v*)&rp[mt * 16 + l4 * 4];
    S[mt][0] = fmaf(S[mt][0], SCALEf, r4.x);
    S[mt][1] = fmaf(S[mt][1], SCALEf, r4.y);
    S[mt][2] = fmaf(S[mt][2], SCALEf, r4.z);
    S[mt][3] = fmaf(S[mt][3], SCALEf, r4.w);
    mx = fmaxf(mx, fmaxf(fmaxf(S[mt][0], S[mt][1]), fmaxf(S[mt][2], S[mt][3])));
  }
  mx = fmaxf(mx, __shfl_xor(mx, 16, 64));
  mx = fmaxf(mx, __shfl_xor(mx, 32, 64));
  float sum = 0.f;
#pragma unroll
  for (int mt = 0; mt < 16; mt++) {
    S[mt][0] = __expf(S[mt][0] - mx);
    S[mt][1] = __expf(S[mt][1] - mx);
    S[mt][2] = __expf(S[mt][2] - mx);
    S[mt][3] = __expf(S[mt][3] - mx);
    sum += (S[mt][0] + S[mt][1]) + (S[mt][2] + S[mt][3]);
  }
  sum += __shfl_xor(sum, 16, 64);
  sum += __shfl_xor(sum, 32, 64);
  const float inv = __builtin_amdgcn_rcpf(sum);
  unsigned short* ap = attn + (((long)b * NHh + h) * Nn + n) * Mm;
#pragma unroll
  for (int mt = 0; mt < 16; mt++) {
    const unsigned p0 = cvtpk(S[mt][0] * inv, S[mt][1] * inv);
    const unsigned p1 = cvtpk(S[mt][2] * inv, S[mt][3] * inv);
    *(uint2*)&ap[mt * 16 + l4 * 4] = make_uint2(p0, p1);
  }
}

// ------------- Gram matrix G[b][36*STP] (line-spread atomics, R22 2-chunk) -------------
__launch_bounds__(256)
__global__ void gram_stats(const unsigned short* __restrict__ attn, float* __restrict__ G)
{
  __shared__ float red[36][4];
  const int b = blockIdx.y, tid = threadIdx.x;
  const unsigned short* ap = attn + (long)b * NHh * NMs + (long)blockIdx.x * 4096 + tid * 8;
  float g[36] = {};
#pragma unroll
  for (int half = 0; half < 2; half++) {
    const unsigned short* app = ap + half * 2048;
    float a[8][8];
#pragma unroll
    for (int h = 0; h < 8; h++) {
      const uint4 v = *(const uint4*)&app[(long)h * NMs];
      a[h][0] = bflo(v.x); a[h][1] = bfhi(v.x); a[h][2] = bflo(v.y); a[h][3] = bfhi(v.y);
      a[h][4] = bflo(v.z); a[h][5] = bfhi(v.z); a[h][6] = bflo(v.w); a[h][7] = bfhi(v.w);
    }
    int t = 0;
#pragma unroll
    for (int i = 0; i < 8; i++)
#pragma unroll
      for (int j = i; j < 8; j++, t++) {
        float s = 0.f;
#pragma unroll
        for (int m = 0; m < 8; m++) s = fmaf(a[i][m], a[j][m], s);
        g[t] += s;
      }
  }
  const int lane = tid & 63, wid = tid >> 6;
#pragma unroll
  for (int t2 = 0; t2 < 36; t2++) {
    const float s = wave_sum(g[t2]);
    if (lane == 0) red[t2][wid] = s;
  }
  __syncthreads();
  if (tid < 36)
    atomicAdd(&G[((long)b * 36 + tid) * STP],
              red[tid][0] + red[tid][1] + red[tid][2] + red[tid][3]);
}

// ------------- pass B: expand+gn1(from G)+swish -> conv3x3 -> x2(bf16) + gn2 stats ----
// R18/R7 geometry + R23 phase-split staging (neutral but kept). R24: ALL pure pair-wise
// v2f arithmetic forced to v_pk_*_f32 via inline asm (conv 36->18 ops/row, stats
// 16->8); expand unpack guaranteed 1-op (uint2 + bflo/bfhi). Identical numerics.
__launch_bounds__(768, 6)
__global__ void dla_pass_b(const unsigned short* __restrict__ attn,
                           const float* __restrict__ Wexp,
                           const float* __restrict__ g1, const float* __restrict__ b1,
                           const float* __restrict__ G, const float* __restrict__ Wdw,
                           unsigned short* __restrict__ x2, float* __restrict__ stats2c, int b0)
{
  __shared__ __align__(16) unsigned short sl[(TTB + 2) * NHh * Mm];  // 73728 B
  const int tid = threadIdx.x;
  const int wv = tid >> 6, lane = tid & 63;   // wv 0..11
  const int bc = blockIdx.y, b = b0 + bc;
  const int n0 = blockIdx.x * TTB;
  const int c0 = wv * 2;        // channel pair owned by this wave
  const int g = wv >> 2;        // GN group (channels 0-7 / 8-15 / 16-23)

  const unsigned short* abase = attn + (long)b * NHh * NMs;
  const int q_lo = lane >> 5;         // which plane of the pair this lane fills
  const int m0 = (lane & 31) * 8;     // ushort offset within the 512 B plane
  // ---- phase-1 staging: rows 0..9 = planes 0..79 = pairs 0..39 ----
#pragma unroll
  for (int i = 0; i < 4; i++) {
    const int pr = wv + i * 12;
    if (pr < 40) {
      const int pp = pr * 2;
      const int row = pp >> 3;
      const int nn = n0 - 1 + row;
      if (nn >= 0 && nn < Nn) {
        const int h = (pp + q_lo) & 7;
        gload_lds16(abase + (long)h * NMs + (long)nn * Mm + m0, &sl[pp * Mm]);
      }
    }
  }

  // gn1 stats from Gram matrix (mean exact: softmax rows sum to 1)
  float mu, rs;
  {
    const float* Gb = G + (long)b * 36 * STP;
    float sum = 0.f, sumsq = 0.f;
    for (int c = g * 8; c < g * 8 + 8; c++) {
      float w[8];
#pragma unroll
      for (int h = 0; h < 8; h++) w[h] = Wexp[c * 8 + h];
      float wsu = 0.f;
#pragma unroll
      for (int h = 0; h < 8; h++) wsu += w[h];
      sum += wsu;
      float s2 = 0.f;
      int t = 0;
#pragma unroll
      for (int i = 0; i < 8; i++)
#pragma unroll
        for (int j = i; j < 8; j++, t++) {
          const float f = (i == j) ? 1.f : 2.f;
          s2 = fmaf(f * w[i] * w[j], Gb[t * STP], s2);
        }
      sumsq += s2;
    }
    const float cnt = 8.f * NMs;
    mu = sum * ((float)Nn / cnt);
    const float var = sumsq / cnt - mu * mu;
    rs = rsqrtf(var + EPSf);
  }
  // channel-pair (v2f) weights: lane .x -> c0, lane .y -> c0+1 (wave-uniform)
  v2f we2[8], wd2[9], B12;
  {
    const float A10 = rs * g1[c0], A11 = rs * g1[c0 + 1];
    B12.x = b1[c0] - mu * A10;
    B12.y = b1[c0 + 1] - mu * A11;
#pragma unroll
    for (int h = 0; h < NHh; h++) {
      we2[h].x = Wexp[c0 * NHh + h] * A10;
      we2[h].y = Wexp[(c0 + 1) * NHh + h] * A11;
    }
#pragma unroll
    for (int k = 0; k < 9; k++) {
      wd2[k].x = Wdw[c0 * 9 + k];
      wd2[k].y = Wdw[(c0 + 1) * 9 + k];
    }
  }
  __syncthreads();   // barrier 1: phase-1 planes staged

  // ---- phase-2 staging: rows 10..17, overlaps phase-1 compute ----
#pragma unroll
  for (int i = 0; i < 3; i++) {
    const int pr = 40 + wv + i * 12;
    if (pr < 72) {
      const int pp = pr * 2;
      const int row = pp >> 3;
      const int nn = n0 - 1 + row;
      if (nn >= 0 && nn < Nn) {
        const int h = (pp + q_lo) & 7;
        gload_lds16(abase + (long)h * NMs + (long)nn * Mm + m0, &sl[pp * Mm]);
      }
    }
  }

  v2f s1p[4] = {}, s2p[4] = {};
  v2f smp = {0.f, 0.f}, sqp = {0.f, 0.f};
  for (int r = -1; r <= TTB; r++) {
    if (r == 9) __syncthreads();   // barrier 2: phase-2 planes staged (mostly hidden)
    const int nn = n0 + r;
    const bool rowv = (nn >= 0 && nn < Nn);
    v2f xp[4];
    if (rowv) {
#pragma unroll
      for (int mi = 0; mi < 4; mi++) xp[mi] = B12;
      const unsigned short* sp = &sl[(r + 1) * NHh * Mm + lane * 4];
#pragma unroll
      for (int h = 0; h < NHh; h++) {
        const uint2 vv = *(const uint2*)&sp[h * Mm];   // ds_read_b64, 2-way alias
        const float f0 = bflo(vv.x), f1 = bfhi(vv.x);  // 1-op unpack each
        const float f2 = bflo(vv.y), f3 = bfhi(vv.y);
        xp[0] += we2[h] * f0;
        xp[1] += we2[h] * f1;
        xp[2] += we2[h] * f2;
        xp[3] += we2[h] * f3;
      }
#pragma unroll
      for (int mi = 0; mi < 4; mi++) xp[mi] = swish2(xp[mi]);
    } else {
#pragma unroll
      for (int mi = 0; mi < 4; mi++) xp[mi] = (v2f){0.f, 0.f};
    }
    // horizontal halo via shuffles (per component; shfl is 32-bit)
    v2f xl, xr;
    xl.x = __shfl_up(xp[3].x, 1);  xl.y = __shfl_up(xp[3].y, 1);
    xr.x = __shfl_down(xp[0].x, 1); xr.y = __shfl_down(xp[0].y, 1);
    if (lane == 0)  { xl = (v2f){0.f, 0.f}; }
    if (lane == 63) { xr = (v2f){0.f, 0.f}; }
    const v2f L[4] = {xl, xp[0], xp[1], xp[2]};
    const v2f R[4] = {xp[1], xp[2], xp[3], xr};
    v2f y[4];
#pragma unroll
    for (int mi = 0; mi < 4; mi++) {
      v2f u0 = pk_mul(wd2[0], L[mi]);
      u0 = pk_fma(wd2[1], xp[mi], u0);
      u0 = pk_fma(wd2[2], R[mi], u0);
      v2f u1 = pk_mul(wd2[3], L[mi]);
      u1 = pk_fma(wd2[4], xp[mi], u1);
      u1 = pk_fma(wd2[5], R[mi], u1);
      v2f u2 = pk_mul(wd2[6], L[mi]);
      u2 = pk_fma(wd2[7], xp[mi], u2);
      u2 = pk_fma(wd2[8], R[mi], u2);
      y[mi] = pk_add(s2p[mi], u2);
      s2p[mi] = pk_add(s1p[mi], u1);
      s1p[mi] = u0;
    }
    if (r >= 1) {
#pragma unroll
      for (int mi = 0; mi < 4; mi++) {
        smp = pk_add(smp, y[mi]);
        sqp = pk_fma(y[mi], y[mi], sqp);
      }
      const int nw = n0 + r - 1;
      const unsigned w0 = cvtpk(y[0].x, y[1].x), w1 = cvtpk(y[2].x, y[3].x);
      const unsigned w2 = cvtpk(y[0].y, y[1].y), w3 = cvtpk(y[2].y, y[3].y);
      unsigned short* xq = x2 + ((long)(bc * Nn + nw) * HIDh + c0) * Mm + lane * 4;
      *(uint2*)xq        = make_uint2(w0, w1);   // channel c0
      *(uint2*)(xq + Mm) = make_uint2(w2, w3);   // channel c0+1
    }
  }
  {
    const float vs0 = wave_sum(smp.x), vq0 = wave_sum(sqp.x);
    const float vs1 = wave_sum(smp.y), vq1 = wave_sum(sqp.y);
    if (lane == 0) {
      atomicAdd(&stats2c[((long)b * HIDh + c0) * STP], vs0);
      atomicAdd(&stats2c[((long)b * HIDh + c0) * STP + 1], vq0);
      atomicAdd(&stats2c[((long)b * HIDh + c0 + 1) * STP], vs1);
      atomicAdd(&stats2c[((long)b * HIDh + c0 + 1) * STP + 1], vq1);
    }
  }
}

// ------------- pass C: gn2+swish + 1x1 reduce -> a2(bf16) + partial gn3 stats -------
// R21 m-pair packing + R24 forced pk math on the gn/reduce/stats inner loops.
__launch_bounds__(256)
__global__ void dla_pass_c(const unsigned short* __restrict__ x2, const float* __restrict__ g2,
                           const float* __restrict__ b2, const float* __restrict__ stats2c,
                           const float* __restrict__ Wred, unsigned short* __restrict__ a2,
                           float* __restrict__ partial3, int b0)
{
  __shared__ float wA[HIDh], wB[HIDh], wrs[HIDh][NHh];
  __shared__ float red2s[2][4];
  const int tid = threadIdx.x;
  const int wv = tid >> 6, lane = tid & 63;
  const int bc = blockIdx.y, b = b0 + bc;
  if (tid < HIDh) {
    const int c = tid, g = c >> 3;
    float s = 0.f, q = 0.f;
#pragma unroll
    for (int cc = 0; cc < 8; cc++) {
      s += stats2c[((long)b * HIDh + g * 8 + cc) * STP];
      q += stats2c[((long)b * HIDh + g * 8 + cc) * STP + 1];
    }
    const float cnt = 8.f * NMs;
    const float mu = s / cnt;
    const float var = q / cnt - mu * mu;
    const float A2 = rsqrtf(var + EPSf) * g2[c];
    wA[c] = A2; wB[c] = b2[c] - mu * A2;
  }
  if (tid < HIDh * NHh) {
    const int c = tid >> 3, h = tid & 7;
    wrs[c][h] = Wred[h * HIDh + c];
  }
  __syncthreads();
  const int rsel = lane >> 5, ms = lane & 31;
  const int n = blockIdx.x * 8 + wv * 2 + rsel;
  const unsigned short* xp = x2 + (long)(bc * Nn + n) * HIDh * Mm + ms * 8;
  v2f red[NHh][4] = {};    // m-pairs: [mi] covers m = 2mi, 2mi+1
#pragma unroll
  for (int c = 0; c < HIDh; c++) {
    const uint4 xv = *(const uint4*)&xp[c * Mm];
    const v2f A2 = {wA[c], wA[c]}, B2 = {wB[c], wB[c]};
    v2f xw[4];
    xw[0] = (v2f){bflo(xv.x), bfhi(xv.x)};
    xw[1] = (v2f){bflo(xv.y), bfhi(xv.y)};
    xw[2] = (v2f){bflo(xv.z), bfhi(xv.z)};
    xw[3] = (v2f){bflo(xv.w), bfhi(xv.w)};
#pragma unroll
    for (int mi = 0; mi < 4; mi++) xw[mi] = swish2(pk_fma(xw[mi], A2, B2));
#pragma unroll
    for (int h = 0; h < NHh; h++) {
      const float w = wrs[c][h];
      const v2f w2 = {w, w};
#pragma unroll
      for (int mi = 0; mi < 4; mi++) red[h][mi] = pk_fma(w2, xw[mi], red[h][mi]);
    }
  }
  v2f s3v = {0.f, 0.f}, q3v = {0.f, 0.f};
#pragma unroll
  for (int h = 0; h < NHh; h++) {
    uint4 st;
    st.x = cvtpk(red[h][0].x, red[h][0].y);
    st.y = cvtpk(red[h][1].x, red[h][1].y);
    st.z = cvtpk(red[h][2].x, red[h][2].y);
    st.w = cvtpk(red[h][3].x, red[h][3].y);
    *(uint4*)&a2[(((long)b * NHh + h) * Nn + n) * Mm + ms * 8] = st;
#pragma unroll
    for (int mi = 0; mi < 4; mi++) {
      s3v = pk_add(s3v, red[h][mi]);
      q3v = pk_fma(red[h][mi], red[h][mi], q3v);
    }
  }
  float s3 = s3v.x + s3v.y, q3 = q3v.x + q3v.y;
  s3 = wave_sum(s3); q3 = wave_sum(q3);
  if (lane == 0) { red2s[0][wv] = s3; red2s[1][wv] = q3; }
  __syncthreads();
  if (tid < 2) {
    float t = red2s[tid][0] + red2s[tid][1] + red2s[tid][2] + red2s[tid][3];
    partial3[((long)b * 128 + blockIdx.x) * 2 + tid] = t;
  }
}

// ------------- pv_mfma: gn3 (in-kernel stats3+sv reduce) + PV via MFMA -> oT (bf16) ----
__launch_bounds__(256)
__global__ void pv_mfma(const unsigned short* __restrict__ a2, const unsigned short* __restrict__ vb,
                        const float* __restrict__ partial3,
                        const float* __restrict__ g3, const float* __restrict__ b3,
                        unsigned short* __restrict__ o)
{
  __shared__ __align__(16) unsigned short Vt[32 * 264];   // [d][m] bf16, +8 pad
  __shared__ float svl[32][9];
  __shared__ float r4s[4];
  const int b = blockIdx.z, h = blockIdx.y, n0 = blockIdx.x * 128;
  const int tid = threadIdx.x;
  const int lane = tid & 63, wv = tid >> 6;
  const int l15 = lane & 15, l4 = lane >> 4;
  // stage V^T (bf16 copy): vb is [m][d]
  {
    const unsigned short* vp = vb + ((long)b * NHh + h) * Mm * HDd;
#pragma unroll
    for (int u = 0; u < 32; u++) {
      const int idx = tid + u * 256;
      const int m = idx >> 5, d = idx & 31;
      Vt[d * 264 + m] = vp[idx];
    }
  }
  // stats3 reduce: waves 0,1 cover sum halves; waves 2,3 sumsq halves
  float pv_;
  {
    const int half = tid >> 7, i = tid & 127;
    pv_ = partial3[((long)b * 128 + i) * 2 + half];
  }
  __syncthreads();   // Vt staged
  // sv partials: thread (d = tid&31, seg = tid>>5) sums 32 m's from LDS
  {
    const int d = tid & 31, seg = tid >> 5;
    float s = 0.f;
#pragma unroll
    for (int mm = 0; mm < 32; mm++) s += bfup(Vt[d * 264 + seg * 32 + mm]);
    svl[d][seg] = s;
  }
  {
    const float w = wave_sum(pv_);
    if (lane == 0) r4s[wv] = w;
  }
  __syncthreads();
  if (tid < 32) {
    float t = 0.f;
#pragma unroll
    for (int seg = 0; seg < 8; seg++) t += svl[tid][seg];
    svl[tid][0] = t;
  }
  __syncthreads();
  const float cnt = (float)(NHh * NMs);
  const float mu = (r4s[0] + r4s[1]) / cnt;
  const float var = (r4s[2] + r4s[3]) / cnt - mu * mu;
  const float r3 = rsqrtf(var + EPSf);
  const float alpha = r3 * g3[h];
  const float beta = b3[h] - mu * alpha;

  const unsigned short* ap = a2 + (((long)b * NHh + h) * Nn + n0) * Mm;
  f4v acc[2][2] = {};   // [fm: d-tile][fn: n-tile]
#pragma unroll 2
  for (int k0 = 0; k0 < Mm; k0 += 32) {
    bf8v af[2], bf[2];
#pragma unroll
    for (int fm = 0; fm < 2; fm++)   // A = V^T: m-index = d
      af[fm] = *(const bf8v*)&Vt[(fm * 16 + l15) * 264 + k0 + l4 * 8];
#pragma unroll
    for (int fn = 0; fn < 2; fn++)   // B = a2^T: n-index = attn row
      bf[fn] = *(const bf8v*)&ap[(long)(wv * 32 + fn * 16 + l15) * Mm + k0 + l4 * 8];
#pragma unroll
    for (int fm = 0; fm < 2; fm++)
#pragma unroll
      for (int fn = 0; fn < 2; fn++)
        acc[fm][fn] = __builtin_amdgcn_mfma_f32_16x16x32_bf16(af[fm], bf[fn], acc[fm][fn], 0, 0, 0);
  }
#pragma unroll
  for (int fm = 0; fm < 2; fm++) {
#pragma unroll
    for (int r = 0; r < 4; r++) {
      const int d = fm * 16 + l4 * 4 + r;
      const float bv = beta * svl[d][0];
      unsigned short* op = o + ((long)b * Cc + h * HDd + d) * Nn + n0 + wv * 32 + l15;
#pragma unroll
      for (int fn = 0; fn < 2; fn++)
        op[fn * 16] = f2bf(fmaf(alpha, acc[fm][fn][r], bv));   // bf16 oT
    }
  }
}

extern "C" void kernel_launch(void* const* d_in, const int* in_sizes, int n_in,
                              void* d_out, int out_size, void* d_ws, size_t ws_size,
                              hipStream_t stream) {
  const float* q    = (const float*)d_in[0];
  const float* kv   = (const float*)d_in[1];
  const float* Wq   = (const float*)d_in[2];
  const float* Wkv  = (const float*)d_in[3];
  const float* Wp   = (const float*)d_in[4];
  const float* bp   = (const float*)d_in[5];
  const float* rpb  = (const float*)d_in[6];
  const float* Wexp = (const float*)d_in[7];
  const float* g1   = (const float*)d_in[8];
  const float* b1   = (const float*)d_in[9];
  const float* Wdw  = (const float*)d_in[10];
  const float* g2   = (const float*)d_in[11];
  const float* b2   = (const float*)d_in[12];
  const float* Wred = (const float*)d_in[13];
  const float* g3   = (const float*)d_in[14];
  const float* b3   = (const float*)d_in[15];
  float* out = (float*)d_out;

  float* ws = (float*)d_ws;
  size_t off = 0;
  auto alloc = [&](size_t n) { float* p = ws + off; off += n; return p; };
  float* attnf   = alloc((size_t)Bb * NHh * NMs / 2);      // 67.1 MB (bf16)
  float* a2f     = alloc((size_t)Bb * NHh * NMs / 2);      // 67.1 MB (bf16)
  float* big     = alloc((size_t)CHUNK * HIDh * NMs / 2);  // 100.7 MB: qhT -> x2 -> oT
  float* kbuf    = alloc((size_t)Bb * NHh * Mm * HDd);     // bf16 (half used)
  float* vbuf    = alloc((size_t)Bb * NHh * Mm * HDd);     // bf16 (half used)
  float* G       = alloc((size_t)Bb * 36 * STP);           // line-spread
  float* stats2c = alloc((size_t)Bb * HIDh * STP);         // line-spread
  float* partial3= alloc((size_t)Bb * 128 * 2);            // fully overwritten, no memset
  unsigned short* attn = (unsigned short*)attnf;
  unsigned short* a2 = (unsigned short*)a2f;
  unsigned short* kb16 = (unsigned short*)kbuf;
  unsigned short* vb16 = (unsigned short*)vbuf;
  unsigned short* qhT16 = (unsigned short*)big;  // bf16, dead after attn_softmax
  unsigned short* x2 = (unsigned short*)big;     // alive during DLA chunk loop
  unsigned short* oT16 = (unsigned short*)big;   // bf16, alive after last pass C

  // zero only the atomic-accumulated buffers (G | stats2c are contiguous)
  hipMemsetAsync(G, 0, (size_t)(Bb * 36 * STP + Bb * HIDh * STP) * sizeof(float), stream);

  // q-projection: qhT (bf16) = Wq x q  (MFMA bf16, bf16 store)
  gemm_mfma<0, 0><<<dim3(Nn / 64, Cc / 64, Bb), 256, 0, stream>>>(
      q, Wq, nullptr, (float*)qhT16, nullptr, Nn);
  // kv-projection: scatter bf16 into kbuf/vbuf [b,h,m,d]  (MFMA bf16)
  gemm_mfma<1, 0><<<dim3(Mm / 64, 512 / 64, Bb), 256, 0, stream>>>(
      kv, Wkv, nullptr, kbuf, vbuf, Mm);
  attn_softmax<<<dim3(Nn / 64, NHh, Bb), 256, 0, stream>>>(qhT16, kb16, rpb, attn);
  gram_stats<<<dim3(NMs / 4096, Bb), 256, 0, stream>>>(attn, G);

  for (int b0 = 0; b0 < Bb; b0 += CHUNK) {
    dla_pass_b<<<dim3(Nn / TTB, CHUNK), 768, 0, stream>>>(
        attn, Wexp, g1, b1, G, Wdw, x2, stats2c, b0);
    dla_pass_c<<<dim3(Nn / 8, CHUNK), 256, 0, stream>>>(
        x2, g2, b2, stats2c, Wred, a2, partial3, b0);
  }

  pv_mfma<<<dim3(Nn / 128, NHh, Bb), 256, 0, stream>>>(a2, vb16, partial3, g3, b3, oT16);
  // out-projection: out = Wp x oT + bp  (MFMA bf16, bf16 A input)
  gemm_mfma<2, 1><<<dim3(Nn / 64, Cc / 64, Bb), 256, 0, stream>>>(
      (const float*)oT16, Wp, bp, out, nullptr, Nn);
}